// Round 9
// baseline (227.815 us; speedup 1.0000x reference)
//
#include <hip/hip_runtime.h>
#include <math.h>

typedef unsigned short u16;
typedef __bf16 bf16_t;
typedef bf16_t bf16x4 __attribute__((ext_vector_type(4)));
typedef bf16_t bf16x8 __attribute__((ext_vector_type(8)));
typedef short s16x4 __attribute__((ext_vector_type(4)));
typedef float f32x4 __attribute__((ext_vector_type(4)));

typedef const __attribute__((address_space(1))) void* gcp;
typedef __attribute__((address_space(3))) void* lcp;

#define BB 4
#define NN 2048
#define CC 512
#define HH 8
#define HD 64
#define HIDE_ 2048
#define TT (BB*NN)  // 8192

#if __has_builtin(__builtin_amdgcn_exp2f)
#define EXP2(x) __builtin_amdgcn_exp2f(x)
#else
#define EXP2(x) __expf((x) * 0.69314718055994531f)
#endif

#if __has_builtin(__builtin_amdgcn_rcpf)
#define RCP(x) __builtin_amdgcn_rcpf(x)
#else
#define RCP(x) (1.0f / (x))
#endif

__device__ __forceinline__ u16 f2bf(float f) {
  unsigned u = __float_as_uint(f);
  u += 0x7FFF + ((u >> 16) & 1);   // RNE
  return (u16)(u >> 16);
}

// bijective XCD-aware block swizzle (requires nwg % 8 == 0)
__device__ __forceinline__ int xcd_swz(int orig, int nwg) {
  return (orig & 7) * (nwg >> 3) + (orig >> 3);
}

__device__ __forceinline__ void bf8_to_f(const u16* p, float* f) {
  uint4 u = *(const uint4*)p;
  f[0] = __uint_as_float(u.x << 16); f[1] = __uint_as_float(u.x & 0xffff0000u);
  f[2] = __uint_as_float(u.y << 16); f[3] = __uint_as_float(u.y & 0xffff0000u);
  f[4] = __uint_as_float(u.z << 16); f[5] = __uint_as_float(u.z & 0xffff0000u);
  f[6] = __uint_as_float(u.w << 16); f[7] = __uint_as_float(u.w & 0xffff0000u);
}

// load 8 fp32, scale, pack to bf16x8
__device__ __forceinline__ bf16x8 ldq8(const float* p, float s) {
  float4 a = *(const float4*)p;
  float4 b = *(const float4*)(p + 4);
  bf16x8 r = {(bf16_t)(a.x * s), (bf16_t)(a.y * s), (bf16_t)(a.z * s), (bf16_t)(a.w * s),
              (bf16_t)(b.x * s), (bf16_t)(b.y * s), (bf16_t)(b.z * s), (bf16_t)(b.w * s)};
  return r;
}

// tanh-form GELU
__device__ __forceinline__ float gelu_tanh(float x) {
  float y = 0.7978845608028654f * x * (1.0f + 0.044715f * x * x);
  float a = y * 2.8853900817779268f;
  a = fminf(fmaxf(a, -30.0f), 30.0f);
  float e = EXP2(a);
  float t = (e - 1.0f) * RCP(e + 1.0f);
  return 0.5f * x * (1.0f + t);
}

// ---------------- prep: k cvt + V^T transpose (w1/w2 conversion moved into attn launch) ----------------
__global__ __launch_bounds__(256) void prep_kernel(const float* __restrict__ k,
                                                   const float* __restrict__ v,
                                                   u16* __restrict__ kb,
                                                   u16* __restrict__ vtb) {
  __shared__ __align__(16) u16 T[64 * 72];
  int bid = blockIdx.x, tid = threadIdx.x;
  if (bid < 2048) {
    int i = (bid * 256 + tid) * 8;
    float4 a = *(const float4*)(k + i);
    float4 b2 = *(const float4*)(k + i + 4);
    u16 r[8] = {f2bf(a.x), f2bf(a.y), f2bf(a.z), f2bf(a.w),
                f2bf(b2.x), f2bf(b2.y), f2bf(b2.z), f2bf(b2.w)};
    *(uint4*)(kb + i) = *(const uint4*)r;
    return;
  }
  int tv = bid - 2048;
  int j0 = (tv & 31) * 64;
  int bh = tv >> 5;
  int b = bh >> 3, h = bh & 7;
  // fill: float4 reads along d, transposed scalar LDS writes
#pragma unroll
  for (int i = 0; i < 4; i++) {
    int idx = i * 256 + tid;
    int j = idx >> 4, dq = idx & 15;
    float4 a = *(const float4*)(v + ((size_t)(b * NN + j0 + j)) * CC + h * 64 + dq * 4);
    T[(dq * 4 + 0) * 72 + j] = f2bf(a.x);
    T[(dq * 4 + 1) * 72 + j] = f2bf(a.y);
    T[(dq * 4 + 2) * 72 + j] = f2bf(a.z);
    T[(dq * 4 + 3) * 72 + j] = f2bf(a.w);
  }
  __syncthreads();
  // drain: uint4 (8 u16) per thread, 128B-contiguous global segments
#pragma unroll
  for (int i = 0; i < 2; i++) {
    int idx = i * 256 + tid;
    int d = idx >> 3, jb = idx & 7;
    uint4 val = *(const uint4*)&T[d * 72 + jb * 8];
    *(uint4*)&vtb[((size_t)(bh * 64 + d)) * NN + j0 + jb * 8] = val;
  }
}

// ---------------- flash attention + co-resident w1/w2 conversion ----------------
// attn blocks: raw 0..1023 (round-5 structure, 54us). raw 1024..2047: fc1_w/fc2_w
// fp32->bf16 conversion riding on spare occupancy (attn = 4 blocks/CU of 8 allowed)
// and spare HBM BW (attn at ~8%). No LDS/barriers on the conv path.
__global__ __launch_bounds__(256, 4) void attn_kernel(const float* __restrict__ qf,
                                                      const u16* __restrict__ kb,
                                                      const u16* __restrict__ vtb,
                                                      const float* __restrict__ fc1w,
                                                      const float* __restrict__ fc2w,
                                                      u16* __restrict__ w1b,
                                                      u16* __restrict__ w2b,
                                                      u16* __restrict__ ou,
                                                      float* __restrict__ lsum,
                                                      float qs) {
  __shared__ __align__(16) u16 Ks[64 * 64];
  __shared__ __align__(16) u16 Vs[64 * 64];
  int raw = blockIdx.x;
  int tid = threadIdx.x;
  if (raw >= 1024) {
    int cid = raw - 1024;
    const float* in = (cid < 512) ? fc1w : fc2w;
    u16* outp = (cid < 512) ? w1b : w2b;
    int rel = cid & 511;
    int i = (rel * 256 + tid) * 8;
    float4 a = *(const float4*)(in + i);
    float4 b2 = *(const float4*)(in + i + 4);
    u16 r[8] = {f2bf(a.x), f2bf(a.y), f2bf(a.z), f2bf(a.w),
                f2bf(b2.x), f2bf(b2.y), f2bf(b2.z), f2bf(b2.w)};
    *(uint4*)(outp + i) = *(const uint4*)r;
    return;
  }
  int wave = tid >> 6, lane = tid & 63;
  int l15 = lane & 15, quad = lane >> 4;
  int r7 = lane & 7; r7 = l15 & 7;
  int half = raw >> 9;
  int bid = xcd_swz(raw & 511, 512);
  int qt = bid & 15, h = (bid >> 4) & 7, b = bid >> 7;
  int qw = qt * 128 + wave * 32;
  int j0base = half * 1024;

  u16* ou_ = ou + (size_t)half * TT * CC;
  float* ls_ = lsum + (size_t)half * TT * HH;

  const float* qp = qf + ((size_t)(b * NN + qw + l15)) * CC + h * 64 + quad * 8;
  bf16x8 qfA0 = ldq8(qp, qs);
  bf16x8 qfA1 = ldq8(qp + 32, qs);
  bf16x8 qfB0 = ldq8(qp + (size_t)16 * CC, qs);
  bf16x8 qfB1 = ldq8(qp + (size_t)16 * CC + 32, qs);

  int rl = lane >> 3;
  int cb = (lane & 7) ^ rl;
  int rK = wave * 16 + rl;
  size_t vtbase = ((size_t)(b * HH + h)) * 64 * NN;
  const u16* kp0 = kb + ((size_t)(b * NN + j0base + rK)) * CC + h * 64 + cb * 8;
  const u16* kp1 = kp0 + (size_t)8 * CC;
  const u16* vp0 = vtb + vtbase + (size_t)rK * NN + j0base + cb * 8;
  const u16* vp1 = vp0 + (size_t)8 * NN;
  lcp lK0 = (lcp)&Ks[wave * 16 * 64];
  lcp lK1 = (lcp)&Ks[wave * 16 * 64 + 8 * 64];
  lcp lV0 = (lcp)&Vs[wave * 16 * 64];
  lcp lV1 = (lcp)&Vs[wave * 16 * 64 + 8 * 64];

  float lA = 0.f, lB = 0.f;
  f32x4 oA[4] = {}, oB[4] = {};

  for (int kt = 0; kt < 16; kt++) {
    __syncthreads();
    __builtin_amdgcn_global_load_lds((gcp)kp0, lK0, 16, 0, 0);
    __builtin_amdgcn_global_load_lds((gcp)kp1, lK1, 16, 0, 0);
    __builtin_amdgcn_global_load_lds((gcp)vp0, lV0, 16, 0, 0);
    __builtin_amdgcn_global_load_lds((gcp)vp1, lV1, 16, 0, 0);
    kp0 += (size_t)64 * CC; kp1 += (size_t)64 * CC;
    vp0 += 64; vp1 += 64;
    __syncthreads();

    s16x4 pfA[4], pfB[4];
    __builtin_amdgcn_s_setprio(1);
#pragma unroll
    for (int nt = 0; nt < 4; nt++) {
      const u16* krow = &Ks[(nt * 16 + l15) * 64];
      bf16x8 k0 = *(const bf16x8*)&krow[(quad ^ r7) * 8];
      bf16x8 k1 = *(const bf16x8*)&krow[((quad + 4) ^ r7) * 8];
      f32x4 zA = {0.f, 0.f, 0.f, 0.f}, zB = {0.f, 0.f, 0.f, 0.f};
      zA = __builtin_amdgcn_mfma_f32_16x16x32_bf16(k0, qfA0, zA, 0, 0, 0);
      zA = __builtin_amdgcn_mfma_f32_16x16x32_bf16(k1, qfA1, zA, 0, 0, 0);
      zB = __builtin_amdgcn_mfma_f32_16x16x32_bf16(k0, qfB0, zB, 0, 0, 0);
      zB = __builtin_amdgcn_mfma_f32_16x16x32_bf16(k1, qfB1, zB, 0, 0, 0);
      float a0 = EXP2(zA[0]), a1 = EXP2(zA[1]), a2 = EXP2(zA[2]), a3 = EXP2(zA[3]);
      float b0 = EXP2(zB[0]), b1 = EXP2(zB[1]), b2 = EXP2(zB[2]), b3 = EXP2(zB[3]);
      lA += (a0 + a1) + (a2 + a3);
      lB += (b0 + b1) + (b2 + b3);
      bf16x4 ta = {(bf16_t)a0, (bf16_t)a1, (bf16_t)a2, (bf16_t)a3};
      bf16x4 tb = {(bf16_t)b0, (bf16_t)b1, (bf16_t)b2, (bf16_t)b3};
      pfA[nt] = __builtin_bit_cast(s16x4, ta);
      pfB[nt] = __builtin_bit_cast(s16x4, tb);
    }
#pragma unroll
    for (int dt = 0; dt < 4; dt++) {
      const u16* vrow = &Vs[(dt * 16 + l15) * 64];
#pragma unroll
      for (int nt = 0; nt < 4; nt++) {
        s16x4 vf = *(const s16x4*)
            &vrow[((nt * 2 + (quad >> 1)) ^ r7) * 8 + (quad & 1) * 4];
        oA[dt] = __builtin_amdgcn_mfma_f32_16x16x16bf16_1k(vf, pfA[nt], oA[dt], 0, 0, 0);
        oB[dt] = __builtin_amdgcn_mfma_f32_16x16x16bf16_1k(vf, pfB[nt], oB[dt], 0, 0, 0);
      }
    }
    __builtin_amdgcn_s_setprio(0);
  }

  lA += __shfl_xor(lA, 16, 64);
  lA += __shfl_xor(lA, 32, 64);
  lB += __shfl_xor(lB, 16, 64);
  lB += __shfl_xor(lB, 32, 64);
  if (quad == 0) {
    ls_[(size_t)(b * NN + qw + l15) * HH + h] = lA;
    ls_[(size_t)(b * NN + qw + 16 + l15) * HH + h] = lB;
  }
  size_t obase = ((size_t)(b * NN + qw + l15)) * CC + h * 64 + quad * 4;
#pragma unroll
  for (int dt = 0; dt < 4; dt++) {
    u16 ra[4] = {f2bf(oA[dt][0]), f2bf(oA[dt][1]), f2bf(oA[dt][2]), f2bf(oA[dt][3])};
    u16 rb[4] = {f2bf(oB[dt][0]), f2bf(oB[dt][1]), f2bf(oB[dt][2]), f2bf(oB[dt][3])};
    *(uint2*)&ou_[obase + dt * 16] = *(const uint2*)ra;
    *(uint2*)&ou_[obase + (size_t)16 * CC + dt * 16] = *(const uint2*)rb;
  }
}

// ---------------- ln1: combine bf16 O_u halves + fp32 q residual + LN -> bf16 ----------------
__global__ __launch_bounds__(256) void ln1_kernel(const float* __restrict__ q,
                                                  const u16* __restrict__ ou,
                                                  const float* __restrict__ lsum,
                                                  const float* __restrict__ w,
                                                  const float* __restrict__ bb,
                                                  u16* __restrict__ outb) {
  int tid = threadIdx.x;
  int row = blockIdx.x * 4 + (tid >> 6);
  int lane = tid & 63;
  int h = lane >> 3;
  size_t base = (size_t)row * CC + lane * 8;
  const u16* ou1 = ou + (size_t)TT * CC;
  const float* ls1 = lsum + (size_t)TT * HH;
  float li = lsum[(size_t)row * HH + h] + ls1[(size_t)row * HH + h];
  float inv = 1.0f / li;
  float4 a0 = *(const float4*)(q + base);
  float4 a1 = *(const float4*)(q + base + 4);
  float c[8], d[8];
  bf8_to_f(ou + base, c);
  bf8_to_f(ou1 + base, d);
  float av[8] = {a0.x, a0.y, a0.z, a0.w, a1.x, a1.y, a1.z, a1.w};
  float x[8];
#pragma unroll
  for (int i = 0; i < 8; i++) x[i] = av[i] + (c[i] + d[i]) * inv;
  float sum = 0.f, sq = 0.f;
#pragma unroll
  for (int i = 0; i < 8; i++) { sum += x[i]; sq += x[i] * x[i]; }
#pragma unroll
  for (int msk = 1; msk < 64; msk <<= 1) {
    sum += __shfl_xor(sum, msk, 64);
    sq += __shfl_xor(sq, msk, 64);
  }
  float mu = sum * (1.0f / CC);
  float var = sq * (1.0f / CC) - mu * mu;
  float rs = rsqrtf(var + 1e-6f);
  int col = lane * 8;
  float4 w0 = *(const float4*)(w + col);
  float4 w1 = *(const float4*)(w + col + 4);
  float4 b0 = *(const float4*)(bb + col);
  float4 b1 = *(const float4*)(bb + col + 4);
  float wv[8] = {w0.x, w0.y, w0.z, w0.w, w1.x, w1.y, w1.z, w1.w};
  float bv[8] = {b0.x, b0.y, b0.z, b0.w, b1.x, b1.y, b1.z, b1.w};
  u16 r[8];
#pragma unroll
  for (int i = 0; i < 8; i++) r[i] = f2bf((x[i] - mu) * rs * wv[i] + bv[i]);
  *(uint4*)(outb + base) = *(const uint4*)r;
}

// ---------------- ln2: bf16 residual + bf16 split-K partials (x2) + bias + LN ----------------
__global__ __launch_bounds__(256) void ln2_kernel(const u16* __restrict__ q2b,
                                                  const u16* __restrict__ mp,
                                                  const float* __restrict__ fb,
                                                  const float* __restrict__ w,
                                                  const float* __restrict__ bb,
                                                  float* __restrict__ outf) {
  int tid = threadIdx.x;
  int row = blockIdx.x * 4 + (tid >> 6);
  int lane = tid & 63;
  size_t base = (size_t)row * CC + lane * 8;
  const u16* mp1 = mp + (size_t)TT * CC;
  int col = lane * 8;
  float a[8], c[8], d[8];
  bf8_to_f(q2b + base, a);
  bf8_to_f(mp + base, c);
  bf8_to_f(mp1 + base, d);
  float4 f0 = *(const float4*)(fb + col);
  float4 f1 = *(const float4*)(fb + col + 4);
  float fbv[8] = {f0.x, f0.y, f0.z, f0.w, f1.x, f1.y, f1.z, f1.w};
  float x[8];
#pragma unroll
  for (int i = 0; i < 8; i++) x[i] = a[i] + (c[i] + d[i]) + fbv[i];
  float sum = 0.f, sq = 0.f;
#pragma unroll
  for (int i = 0; i < 8; i++) { sum += x[i]; sq += x[i] * x[i]; }
#pragma unroll
  for (int msk = 1; msk < 64; msk <<= 1) {
    sum += __shfl_xor(sum, msk, 64);
    sq += __shfl_xor(sq, msk, 64);
  }
  float mu = sum * (1.0f / CC);
  float var = sq * (1.0f / CC) - mu * mu;
  float rs = rsqrtf(var + 1e-6f);
  float4 w0 = *(const float4*)(w + col);
  float4 w1 = *(const float4*)(w + col + 4);
  float4 b0 = *(const float4*)(bb + col);
  float4 b1 = *(const float4*)(bb + col + 4);
  float wv[8] = {w0.x, w0.y, w0.z, w0.w, w1.x, w1.y, w1.z, w1.w};
  float bv[8] = {b0.x, b0.y, b0.z, b0.w, b1.x, b1.y, b1.z, b1.w};
  float y[8];
#pragma unroll
  for (int i = 0; i < 8; i++) y[i] = (x[i] - mu) * rs * wv[i] + bv[i];
  *(float4*)(outf + base) = make_float4(y[0], y[1], y[2], y[3]);
  *(float4*)(outf + base + 4) = make_float4(y[4], y[5], y[6], y[7]);
}

// ---------------- GEMM 128x128 tile, BK=64, 4 waves, dbuf + counted-vmcnt, 2 blocks/CU ----------
// Epilogue stages C through the (dead) staging LDS with pitch 140 (conflict-free writes,
// quad bank offsets {0,24,16,8}) and stores uint2 -> 256B-contiguous global segments.
template <bool GELU>
__global__ __launch_bounds__(256) void gemm128(const u16* __restrict__ A,
                                               const u16* __restrict__ Bw,
                                               const float* __restrict__ bias,
                                               u16* __restrict__ outb,
                                               int Nn, int K, int NT,
                                               int gx, int gy) {
  __shared__ __align__(16) u16 SH[32768];   // [0,16384): As dbuf; [16384,32768): Bs dbuf
  int tid = threadIdx.x, wave = tid >> 6, lane = tid & 63;
  int l15 = lane & 15, quad = lane >> 4;
  int r7 = l15 & 7;
  int l = xcd_swz(blockIdx.x, gridDim.x);
  int bx = l % gx;
  int by = (l / gx) % gy;
  int bz = l / (gx * gy);
  int m0 = by * 128, n0 = bx * 128;
  int kbeg = bz * (NT * 64);
  u16* outz = outb + (size_t)bz * ((size_t)TT * CC);
  int wm = (wave >> 1) * 64, wn = (wave & 1) * 64;
  int w32 = wave * 32;
  int rl = lane >> 3;
  int cb = (lane & 7) ^ rl;
  const u16* Ap = &A[(size_t)(m0 + w32 + rl) * K + kbeg + cb * 8];
  const u16* Bp = &Bw[(size_t)(n0 + w32 + rl) * K + kbeg + cb * 8];
  unsigned sb = w32 * 64;   // wave's staging slice (u16 elems)

  f32x4 acc[4][4] = {};

  auto stage = [&](int buf, int kofs) {
#pragma unroll
    for (int c = 0; c < 4; c++) {
      __builtin_amdgcn_global_load_lds((gcp)(Ap + kofs + (size_t)(c * 8) * K),
          (lcp)&SH[buf * 8192 + sb + c * 512], 16, 0, 0);
      __builtin_amdgcn_global_load_lds((gcp)(Bp + kofs + (size_t)(c * 8) * K),
          (lcp)&SH[16384 + buf * 8192 + sb + c * 512], 16, 0, 0);
    }
  };

  // prologue: 2-deep prefetch
  stage(0, 0);
  stage(1, 64);
  asm volatile("s_waitcnt vmcnt(8)" ::: "memory");   // tile 0 complete
  __builtin_amdgcn_s_barrier();

  for (int t = 0; t < NT; t++) {
    int buf = t & 1;
    bool pf = (t + 2) < NT;
    bf16x8 aF[4][2], bF[4][2];
#pragma unroll
    for (int m = 0; m < 4; m++)
#pragma unroll
      for (int kh = 0; kh < 2; kh++)
        aF[m][kh] = *(const bf16x8*)&SH[buf * 8192 + (wm + m * 16 + l15) * 64 +
                                        ((kh * 4 + quad) ^ r7) * 8];
#pragma unroll
    for (int n = 0; n < 4; n++)
#pragma unroll
      for (int kh = 0; kh < 2; kh++)
        bF[n][kh] = *(const bf16x8*)&SH[16384 + buf * 8192 + (wn + n * 16 + l15) * 64 +
                                        ((kh * 4 + quad) ^ r7) * 8];
    __builtin_amdgcn_s_setprio(1);
#pragma unroll
    for (int m = 0; m < 4; m++)
#pragma unroll
      for (int n = 0; n < 2; n++)
#pragma unroll
        for (int kh = 0; kh < 2; kh++)
          acc[m][n] = __builtin_amdgcn_mfma_f32_16x16x32_bf16(aF[m][kh], bF[n][kh],
                                                              acc[m][n], 0, 0, 0);
    __builtin_amdgcn_s_setprio(0);
    // all LDS reads of buf complete (lgkmcnt 0) in every wave before anyone overwrites
    asm volatile("s_waitcnt lgkmcnt(0)\n\ts_barrier" ::: "memory");
    if (pf) stage(buf, (t + 2) * 64);   // overwrite cur buf: dead (all frags in regs)
    __builtin_amdgcn_s_setprio(1);
#pragma unroll
    for (int m = 0; m < 4; m++)
#pragma unroll
      for (int n = 2; n < 4; n++)
#pragma unroll
        for (int kh = 0; kh < 2; kh++)
          acc[m][n] = __builtin_amdgcn_mfma_f32_16x16x32_bf16(aF[m][kh], bF[n][kh],
                                                              acc[m][n], 0, 0, 0);
    __builtin_amdgcn_s_setprio(0);
    if (t + 1 < NT) {
      if (pf) asm volatile("s_waitcnt vmcnt(8)" ::: "memory");  // t+1's 8 loads done
      else    asm volatile("s_waitcnt vmcnt(0)" ::: "memory");
      __builtin_amdgcn_s_barrier();
      asm volatile("" ::: "memory");
    }
  }

  // epilogue via LDS (two 64-row passes; pitch 140 u16 = 280B)
  const int PIT = 140;
#pragma unroll
  for (int p = 0; p < 2; p++) {
    __syncthreads();
    if ((wave >> 1) == p) {
#pragma unroll
      for (int am = 0; am < 4; am++)
#pragma unroll
        for (int bn = 0; bn < 4; bn++) {
          int colg = n0 + wn + bn * 16 + l15;
          float bcol = GELU ? bias[colg] : 0.0f;
#pragma unroll
          for (int r = 0; r < 4; r++) {
            float val = acc[am][bn][r] + bcol;
            if (GELU) val = gelu_tanh(val);
            SH[(am * 16 + quad * 4 + r) * PIT + wn + bn * 16 + l15] = f2bf(val);
          }
        }
    }
    __syncthreads();
#pragma unroll
    for (int i = 0; i < 8; i++) {
      int idx = i * 256 + tid;          // 0..2047
      int r = idx >> 5;                 // 0..63
      int c4 = idx & 31;                // col = c4*4
      uint2 vv = *(const uint2*)&SH[r * PIT + c4 * 4];
      *(uint2*)&outz[(size_t)(m0 + p * 64 + r) * Nn + n0 + c4 * 4] = vv;
    }
  }
}

extern "C" void kernel_launch(void* const* d_in, const int* in_sizes, int n_in,
                              void* d_out, int out_size, void* d_ws, size_t ws_size,
                              hipStream_t stream) {
  const float* q = (const float*)d_in[0];
  const float* k = (const float*)d_in[1];
  const float* v = (const float*)d_in[2];
  const float* fc1_w = (const float*)d_in[3];
  const float* fc1_b = (const float*)d_in[4];
  const float* fc2_w = (const float*)d_in[5];
  const float* fc2_b = (const float*)d_in[6];
  const float* ln1_w = (const float*)d_in[7];
  const float* ln1_b = (const float*)d_in[8];
  const float* ln2_w = (const float*)d_in[9];
  const float* ln2_b = (const float*)d_in[10];
  float* out = (float*)d_out;

  char* ws = (char*)d_ws;
  size_t off = 0;
  u16* kb = (u16*)(ws + off); off += (size_t)TT * CC * 2;         // 8 MB
  u16* vtb = (u16*)(ws + off); off += (size_t)TT * CC * 2;        // 8 MB
  u16* w1b = (u16*)(ws + off); off += (size_t)HIDE_ * CC * 2;     // 2 MB
  u16* w2b = (u16*)(ws + off); off += (size_t)CC * HIDE_ * 2;     // 2 MB
  u16* ou = (u16*)(ws + off); off += (size_t)2 * TT * CC * 2;     // 16 MB
  float* lsum = (float*)(ws + off); off += (size_t)2 * TT * HH * 4;  // 512 KB
  u16* q2b = (u16*)(ws + off); off += (size_t)TT * CC * 2;        // 8 MB
  u16* hbuf = (u16*)(ws + off); off += (size_t)TT * HIDE_ * 2;    // 32 MB
  u16* mp = (u16*)(ws + off); off += (size_t)2 * TT * CC * 2;     // 16 MB (split-K 2)

  const float QS = 0.18033688011112042f;   // (1/8) * log2(e)
  prep_kernel<<<3072, 256, 0, stream>>>(k, v, kb, vtb);
  attn_kernel<<<2048, 256, 0, stream>>>(q, kb, vtb, fc1_w, fc2_w, w1b, w2b,
                                        ou, lsum, QS);
  ln1_kernel<<<2048, 256, 0, stream>>>(q, ou, lsum, ln1_w, ln1_b, q2b);
  // fc1: M=8192, N=2048, K=512 -> 1024 blocks (gx=16, gy=64), NT=8
  gemm128<true><<<1024, 256, 0, stream>>>(q2b, w1b, fc1_b, hbuf, HIDE_, CC, 8, 16, 64);
  // fc2: M=8192, N=512, K=2048 split-K 2 -> 512 blocks (gx=4, gy=64, z=2), NT=16
  gemm128<false><<<512, 256, 0, stream>>>(hbuf, w2b, fc2_b, mp, CC, HIDE_, 16, 4, 64);
  ln2_kernel<<<2048, 256, 0, stream>>>(q2b, mp, fc2_b, ln2_w, ln2_b, out);
}

// Round 10
// 223.373 us; speedup vs baseline: 1.0199x; 1.0199x over previous
//
#include <hip/hip_runtime.h>
#include <math.h>

typedef unsigned short u16;
typedef __bf16 bf16_t;
typedef bf16_t bf16x4 __attribute__((ext_vector_type(4)));
typedef bf16_t bf16x8 __attribute__((ext_vector_type(8)));
typedef short s16x4 __attribute__((ext_vector_type(4)));
typedef float f32x4 __attribute__((ext_vector_type(4)));

typedef const __attribute__((address_space(1))) void* gcp;
typedef __attribute__((address_space(3))) void* lcp;

#define BB 4
#define NN 2048
#define CC 512
#define HH 8
#define HD 64
#define HIDE_ 2048
#define TT (BB*NN)  // 8192

#if __has_builtin(__builtin_amdgcn_exp2f)
#define EXP2(x) __builtin_amdgcn_exp2f(x)
#else
#define EXP2(x) __expf((x) * 0.69314718055994531f)
#endif

#if __has_builtin(__builtin_amdgcn_rcpf)
#define RCP(x) __builtin_amdgcn_rcpf(x)
#else
#define RCP(x) (1.0f / (x))
#endif

__device__ __forceinline__ u16 f2bf(float f) {
  unsigned u = __float_as_uint(f);
  u += 0x7FFF + ((u >> 16) & 1);   // RNE
  return (u16)(u >> 16);
}

// bijective XCD-aware block swizzle (requires nwg % 8 == 0)
__device__ __forceinline__ int xcd_swz(int orig, int nwg) {
  return (orig & 7) * (nwg >> 3) + (orig >> 3);
}

__device__ __forceinline__ void bf8_to_f(const u16* p, float* f) {
  uint4 u = *(const uint4*)p;
  f[0] = __uint_as_float(u.x << 16); f[1] = __uint_as_float(u.x & 0xffff0000u);
  f[2] = __uint_as_float(u.y << 16); f[3] = __uint_as_float(u.y & 0xffff0000u);
  f[4] = __uint_as_float(u.z << 16); f[5] = __uint_as_float(u.z & 0xffff0000u);
  f[6] = __uint_as_float(u.w << 16); f[7] = __uint_as_float(u.w & 0xffff0000u);
}

// load 8 fp32, scale, pack to bf16x8
__device__ __forceinline__ bf16x8 ldq8(const float* p, float s) {
  float4 a = *(const float4*)p;
  float4 b = *(const float4*)(p + 4);
  bf16x8 r = {(bf16_t)(a.x * s), (bf16_t)(a.y * s), (bf16_t)(a.z * s), (bf16_t)(a.w * s),
              (bf16_t)(b.x * s), (bf16_t)(b.y * s), (bf16_t)(b.z * s), (bf16_t)(b.w * s)};
  return r;
}

// tanh-form GELU
__device__ __forceinline__ float gelu_tanh(float x) {
  float y = 0.7978845608028654f * x * (1.0f + 0.044715f * x * x);
  float a = y * 2.8853900817779268f;
  a = fminf(fmaxf(a, -30.0f), 30.0f);
  float e = EXP2(a);
  float t = (e - 1.0f) * RCP(e + 1.0f);
  return 0.5f * x * (1.0f + t);
}

// ---------------- prep: k cvt + V^T transpose (w1/w2 conversion lives in attn launch) ----------------
__global__ __launch_bounds__(256) void prep_kernel(const float* __restrict__ k,
                                                   const float* __restrict__ v,
                                                   u16* __restrict__ kb,
                                                   u16* __restrict__ vtb) {
  __shared__ __align__(16) u16 T[64 * 72];
  int bid = blockIdx.x, tid = threadIdx.x;
  if (bid < 2048) {
    int i = (bid * 256 + tid) * 8;
    float4 a = *(const float4*)(k + i);
    float4 b2 = *(const float4*)(k + i + 4);
    u16 r[8] = {f2bf(a.x), f2bf(a.y), f2bf(a.z), f2bf(a.w),
                f2bf(b2.x), f2bf(b2.y), f2bf(b2.z), f2bf(b2.w)};
    *(uint4*)(kb + i) = *(const uint4*)r;
    return;
  }
  int tv = bid - 2048;
  int j0 = (tv & 31) * 64;
  int bh = tv >> 5;
  int b = bh >> 3, h = bh & 7;
  // fill: float4 reads along d, transposed scalar LDS writes
#pragma unroll
  for (int i = 0; i < 4; i++) {
    int idx = i * 256 + tid;
    int j = idx >> 4, dq = idx & 15;
    float4 a = *(const float4*)(v + ((size_t)(b * NN + j0 + j)) * CC + h * 64 + dq * 4);
    T[(dq * 4 + 0) * 72 + j] = f2bf(a.x);
    T[(dq * 4 + 1) * 72 + j] = f2bf(a.y);
    T[(dq * 4 + 2) * 72 + j] = f2bf(a.z);
    T[(dq * 4 + 3) * 72 + j] = f2bf(a.w);
  }
  __syncthreads();
  // drain: uint4 (8 u16) per thread, 128B-contiguous global segments
#pragma unroll
  for (int i = 0; i < 2; i++) {
    int idx = i * 256 + tid;
    int d = idx >> 3, jb = idx & 7;
    uint4 val = *(const uint4*)&T[d * 72 + jb * 8];
    *(uint4*)&vtb[((size_t)(bh * 64 + d)) * NN + j0 + jb * 8] = val;
  }
}

// ---------------- flash attention + co-resident w1/w2 conversion ----------------
// attn blocks: raw 0..1023 (round-5 structure). raw 1024..2047: fc1_w/fc2_w fp32->bf16
// conversion riding on spare occupancy and HBM BW. No LDS/barriers on the conv path.
__global__ __launch_bounds__(256, 4) void attn_kernel(const float* __restrict__ qf,
                                                      const u16* __restrict__ kb,
                                                      const u16* __restrict__ vtb,
                                                      const float* __restrict__ fc1w,
                                                      const float* __restrict__ fc2w,
                                                      u16* __restrict__ w1b,
                                                      u16* __restrict__ w2b,
                                                      u16* __restrict__ ou,
                                                      float* __restrict__ lsum,
                                                      float qs) {
  __shared__ __align__(16) u16 Ks[64 * 64];
  __shared__ __align__(16) u16 Vs[64 * 64];
  int raw = blockIdx.x;
  int tid = threadIdx.x;
  if (raw >= 1024) {
    int cid = raw - 1024;
    const float* in = (cid < 512) ? fc1w : fc2w;
    u16* outp = (cid < 512) ? w1b : w2b;
    int rel = cid & 511;
    int i = (rel * 256 + tid) * 8;
    float4 a = *(const float4*)(in + i);
    float4 b2 = *(const float4*)(in + i + 4);
    u16 r[8] = {f2bf(a.x), f2bf(a.y), f2bf(a.z), f2bf(a.w),
                f2bf(b2.x), f2bf(b2.y), f2bf(b2.z), f2bf(b2.w)};
    *(uint4*)(outp + i) = *(const uint4*)r;
    return;
  }
  int wave = tid >> 6, lane = tid & 63;
  int l15 = lane & 15, quad = lane >> 4;
  int r7 = l15 & 7;
  int half = raw >> 9;
  int bid = xcd_swz(raw & 511, 512);
  int qt = bid & 15, h = (bid >> 4) & 7, b = bid >> 7;
  int qw = qt * 128 + wave * 32;
  int j0base = half * 1024;

  u16* ou_ = ou + (size_t)half * TT * CC;
  float* ls_ = lsum + (size_t)half * TT * HH;

  const float* qp = qf + ((size_t)(b * NN + qw + l15)) * CC + h * 64 + quad * 8;
  bf16x8 qfA0 = ldq8(qp, qs);
  bf16x8 qfA1 = ldq8(qp + 32, qs);
  bf16x8 qfB0 = ldq8(qp + (size_t)16 * CC, qs);
  bf16x8 qfB1 = ldq8(qp + (size_t)16 * CC + 32, qs);

  int rl = lane >> 3;
  int cb = (lane & 7) ^ rl;
  int rK = wave * 16 + rl;
  size_t vtbase = ((size_t)(b * HH + h)) * 64 * NN;
  const u16* kp0 = kb + ((size_t)(b * NN + j0base + rK)) * CC + h * 64 + cb * 8;
  const u16* kp1 = kp0 + (size_t)8 * CC;
  const u16* vp0 = vtb + vtbase + (size_t)rK * NN + j0base + cb * 8;
  const u16* vp1 = vp0 + (size_t)8 * NN;
  lcp lK0 = (lcp)&Ks[wave * 16 * 64];
  lcp lK1 = (lcp)&Ks[wave * 16 * 64 + 8 * 64];
  lcp lV0 = (lcp)&Vs[wave * 16 * 64];
  lcp lV1 = (lcp)&Vs[wave * 16 * 64 + 8 * 64];

  float lA = 0.f, lB = 0.f;
  f32x4 oA[4] = {}, oB[4] = {};

  for (int kt = 0; kt < 16; kt++) {
    __syncthreads();
    __builtin_amdgcn_global_load_lds((gcp)kp0, lK0, 16, 0, 0);
    __builtin_amdgcn_global_load_lds((gcp)kp1, lK1, 16, 0, 0);
    __builtin_amdgcn_global_load_lds((gcp)vp0, lV0, 16, 0, 0);
    __builtin_amdgcn_global_load_lds((gcp)vp1, lV1, 16, 0, 0);
    kp0 += (size_t)64 * CC; kp1 += (size_t)64 * CC;
    vp0 += 64; vp1 += 64;
    __syncthreads();

    s16x4 pfA[4], pfB[4];
    __builtin_amdgcn_s_setprio(1);
#pragma unroll
    for (int nt = 0; nt < 4; nt++) {
      const u16* krow = &Ks[(nt * 16 + l15) * 64];
      bf16x8 k0 = *(const bf16x8*)&krow[(quad ^ r7) * 8];
      bf16x8 k1 = *(const bf16x8*)&krow[((quad + 4) ^ r7) * 8];
      f32x4 zA = {0.f, 0.f, 0.f, 0.f}, zB = {0.f, 0.f, 0.f, 0.f};
      zA = __builtin_amdgcn_mfma_f32_16x16x32_bf16(k0, qfA0, zA, 0, 0, 0);
      zA = __builtin_amdgcn_mfma_f32_16x16x32_bf16(k1, qfA1, zA, 0, 0, 0);
      zB = __builtin_amdgcn_mfma_f32_16x16x32_bf16(k0, qfB0, zB, 0, 0, 0);
      zB = __builtin_amdgcn_mfma_f32_16x16x32_bf16(k1, qfB1, zB, 0, 0, 0);
      float a0 = EXP2(zA[0]), a1 = EXP2(zA[1]), a2 = EXP2(zA[2]), a3 = EXP2(zA[3]);
      float b0 = EXP2(zB[0]), b1 = EXP2(zB[1]), b2 = EXP2(zB[2]), b3 = EXP2(zB[3]);
      lA += (a0 + a1) + (a2 + a3);
      lB += (b0 + b1) + (b2 + b3);
      bf16x4 ta = {(bf16_t)a0, (bf16_t)a1, (bf16_t)a2, (bf16_t)a3};
      bf16x4 tb = {(bf16_t)b0, (bf16_t)b1, (bf16_t)b2, (bf16_t)b3};
      pfA[nt] = __builtin_bit_cast(s16x4, ta);
      pfB[nt] = __builtin_bit_cast(s16x4, tb);
    }
#pragma unroll
    for (int dt = 0; dt < 4; dt++) {
      const u16* vrow = &Vs[(dt * 16 + l15) * 64];
#pragma unroll
      for (int nt = 0; nt < 4; nt++) {
        s16x4 vf = *(const s16x4*)
            &vrow[((nt * 2 + (quad >> 1)) ^ r7) * 8 + (quad & 1) * 4];
        oA[dt] = __builtin_amdgcn_mfma_f32_16x16x16bf16_1k(vf, pfA[nt], oA[dt], 0, 0, 0);
        oB[dt] = __builtin_amdgcn_mfma_f32_16x16x16bf16_1k(vf, pfB[nt], oB[dt], 0, 0, 0);
      }
    }
    __builtin_amdgcn_s_setprio(0);
  }

  lA += __shfl_xor(lA, 16, 64);
  lA += __shfl_xor(lA, 32, 64);
  lB += __shfl_xor(lB, 16, 64);
  lB += __shfl_xor(lB, 32, 64);
  if (quad == 0) {
    ls_[(size_t)(b * NN + qw + l15) * HH + h] = lA;
    ls_[(size_t)(b * NN + qw + 16 + l15) * HH + h] = lB;
  }
  size_t obase = ((size_t)(b * NN + qw + l15)) * CC + h * 64 + quad * 4;
#pragma unroll
  for (int dt = 0; dt < 4; dt++) {
    u16 ra[4] = {f2bf(oA[dt][0]), f2bf(oA[dt][1]), f2bf(oA[dt][2]), f2bf(oA[dt][3])};
    u16 rb[4] = {f2bf(oB[dt][0]), f2bf(oB[dt][1]), f2bf(oB[dt][2]), f2bf(oB[dt][3])};
    *(uint2*)&ou_[obase + dt * 16] = *(const uint2*)ra;
    *(uint2*)&ou_[obase + (size_t)16 * CC + dt * 16] = *(const uint2*)rb;
  }
}

// ---------------- ln1: combine bf16 O_u halves + fp32 q residual + LN -> bf16 ----------------
__global__ __launch_bounds__(256) void ln1_kernel(const float* __restrict__ q,
                                                  const u16* __restrict__ ou,
                                                  const float* __restrict__ lsum,
                                                  const float* __restrict__ w,
                                                  const float* __restrict__ bb,
                                                  u16* __restrict__ outb) {
  int tid = threadIdx.x;
  int row = blockIdx.x * 4 + (tid >> 6);
  int lane = tid & 63;
  int h = lane >> 3;
  size_t base = (size_t)row * CC + lane * 8;
  const u16* ou1 = ou + (size_t)TT * CC;
  const float* ls1 = lsum + (size_t)TT * HH;
  float li = lsum[(size_t)row * HH + h] + ls1[(size_t)row * HH + h];
  float inv = 1.0f / li;
  float4 a0 = *(const float4*)(q + base);
  float4 a1 = *(const float4*)(q + base + 4);
  float c[8], d[8];
  bf8_to_f(ou + base, c);
  bf8_to_f(ou1 + base, d);
  float av[8] = {a0.x, a0.y, a0.z, a0.w, a1.x, a1.y, a1.z, a1.w};
  float x[8];
#pragma unroll
  for (int i = 0; i < 8; i++) x[i] = av[i] + (c[i] + d[i]) * inv;
  float sum = 0.f, sq = 0.f;
#pragma unroll
  for (int i = 0; i < 8; i++) { sum += x[i]; sq += x[i] * x[i]; }
#pragma unroll
  for (int msk = 1; msk < 64; msk <<= 1) {
    sum += __shfl_xor(sum, msk, 64);
    sq += __shfl_xor(sq, msk, 64);
  }
  float mu = sum * (1.0f / CC);
  float var = sq * (1.0f / CC) - mu * mu;
  float rs = rsqrtf(var + 1e-6f);
  int col = lane * 8;
  float4 w0 = *(const float4*)(w + col);
  float4 w1 = *(const float4*)(w + col + 4);
  float4 b0 = *(const float4*)(bb + col);
  float4 b1 = *(const float4*)(bb + col + 4);
  float wv[8] = {w0.x, w0.y, w0.z, w0.w, w1.x, w1.y, w1.z, w1.w};
  float bv[8] = {b0.x, b0.y, b0.z, b0.w, b1.x, b1.y, b1.z, b1.w};
  u16 r[8];
#pragma unroll
  for (int i = 0; i < 8; i++) r[i] = f2bf((x[i] - mu) * rs * wv[i] + bv[i]);
  *(uint4*)(outb + base) = *(const uint4*)r;
}

// ---------------- ln2: bf16 residual + bf16 split-K partials (x2) + bias + LN ----------------
__global__ __launch_bounds__(256) void ln2_kernel(const u16* __restrict__ q2b,
                                                  const u16* __restrict__ mp,
                                                  const float* __restrict__ fb,
                                                  const float* __restrict__ w,
                                                  const float* __restrict__ bb,
                                                  float* __restrict__ outf) {
  int tid = threadIdx.x;
  int row = blockIdx.x * 4 + (tid >> 6);
  int lane = tid & 63;
  size_t base = (size_t)row * CC + lane * 8;
  const u16* mp1 = mp + (size_t)TT * CC;
  int col = lane * 8;
  float a[8], c[8], d[8];
  bf8_to_f(q2b + base, a);
  bf8_to_f(mp + base, c);
  bf8_to_f(mp1 + base, d);
  float4 f0 = *(const float4*)(fb + col);
  float4 f1 = *(const float4*)(fb + col + 4);
  float fbv[8] = {f0.x, f0.y, f0.z, f0.w, f1.x, f1.y, f1.z, f1.w};
  float x[8];
#pragma unroll
  for (int i = 0; i < 8; i++) x[i] = a[i] + (c[i] + d[i]) + fbv[i];
  float sum = 0.f, sq = 0.f;
#pragma unroll
  for (int i = 0; i < 8; i++) { sum += x[i]; sq += x[i] * x[i]; }
#pragma unroll
  for (int msk = 1; msk < 64; msk <<= 1) {
    sum += __shfl_xor(sum, msk, 64);
    sq += __shfl_xor(sq, msk, 64);
  }
  float mu = sum * (1.0f / CC);
  float var = sq * (1.0f / CC) - mu * mu;
  float rs = rsqrtf(var + 1e-6f);
  float4 w0 = *(const float4*)(w + col);
  float4 w1 = *(const float4*)(w + col + 4);
  float4 b0 = *(const float4*)(bb + col);
  float4 b1 = *(const float4*)(bb + col + 4);
  float wv[8] = {w0.x, w0.y, w0.z, w0.w, w1.x, w1.y, w1.z, w1.w};
  float bv[8] = {b0.x, b0.y, b0.z, b0.w, b1.x, b1.y, b1.z, b1.w};
  float y[8];
#pragma unroll
  for (int i = 0; i < 8; i++) y[i] = (x[i] - mu) * rs * wv[i] + bv[i];
  *(float4*)(outf + base) = make_float4(y[0], y[1], y[2], y[3]);
  *(float4*)(outf + base + 4) = make_float4(y[4], y[5], y[6], y[7]);
}

// ---------------- GEMM 128x128 tile, BK=64, 4 waves, dbuf + counted-vmcnt, 2 blocks/CU ----------
// Direct global stores (round-8 epilogue — LDS-staged epilogue measured −12us, reverted).
template <bool GELU>
__global__ __launch_bounds__(256) void gemm128(const u16* __restrict__ A,
                                               const u16* __restrict__ Bw,
                                               const float* __restrict__ bias,
                                               u16* __restrict__ outb,
                                               int Nn, int K, int NT,
                                               int gx, int gy) {
  __shared__ __align__(16) u16 As[2][128 * 64];
  __shared__ __align__(16) u16 Bs[2][128 * 64];
  int tid = threadIdx.x, wave = tid >> 6, lane = tid & 63;
  int l15 = lane & 15, quad = lane >> 4;
  int r7 = l15 & 7;
  int l = xcd_swz(blockIdx.x, gridDim.x);
  int bx = l % gx;
  int by = (l / gx) % gy;
  int bz = l / (gx * gy);
  int m0 = by * 128, n0 = bx * 128;
  int kbeg = bz * (NT * 64);
  u16* outz = outb + (size_t)bz * ((size_t)TT * CC);
  int wm = (wave >> 1) * 64, wn = (wave & 1) * 64;
  int w32 = wave * 32;
  int rl = lane >> 3;
  int cb = (lane & 7) ^ rl;
  const u16* Ap = &A[(size_t)(m0 + w32 + rl) * K + kbeg + cb * 8];
  const u16* Bp = &Bw[(size_t)(n0 + w32 + rl) * K + kbeg + cb * 8];
  unsigned sb = w32 * 64;   // wave's staging slice (u16 elems)

  f32x4 acc[4][4] = {};

  auto stage = [&](int buf, int kofs) {
#pragma unroll
    for (int c = 0; c < 4; c++) {
      __builtin_amdgcn_global_load_lds((gcp)(Ap + kofs + (size_t)(c * 8) * K),
          (lcp)&As[buf][sb + c * 512], 16, 0, 0);
      __builtin_amdgcn_global_load_lds((gcp)(Bp + kofs + (size_t)(c * 8) * K),
          (lcp)&Bs[buf][sb + c * 512], 16, 0, 0);
    }
  };

  // prologue: 2-deep prefetch
  stage(0, 0);
  stage(1, 64);
  asm volatile("s_waitcnt vmcnt(8)" ::: "memory");   // tile 0 complete
  __builtin_amdgcn_s_barrier();

  for (int t = 0; t < NT; t++) {
    int buf = t & 1;
    bool pf = (t + 2) < NT;
    bf16x8 aF[4][2], bF[4][2];
#pragma unroll
    for (int m = 0; m < 4; m++)
#pragma unroll
      for (int kh = 0; kh < 2; kh++)
        aF[m][kh] = *(const bf16x8*)&As[buf][(wm + m * 16 + l15) * 64 +
                                            ((kh * 4 + quad) ^ r7) * 8];
#pragma unroll
    for (int n = 0; n < 4; n++)
#pragma unroll
      for (int kh = 0; kh < 2; kh++)
        bF[n][kh] = *(const bf16x8*)&Bs[buf][(wn + n * 16 + l15) * 64 +
                                            ((kh * 4 + quad) ^ r7) * 8];
    __builtin_amdgcn_s_setprio(1);
#pragma unroll
    for (int m = 0; m < 4; m++)
#pragma unroll
      for (int n = 0; n < 2; n++)
#pragma unroll
        for (int kh = 0; kh < 2; kh++)
          acc[m][n] = __builtin_amdgcn_mfma_f32_16x16x32_bf16(aF[m][kh], bF[n][kh],
                                                              acc[m][n], 0, 0, 0);
    __builtin_amdgcn_s_setprio(0);
    // all LDS reads of buf complete (lgkmcnt 0) in every wave before anyone overwrites
    asm volatile("s_waitcnt lgkmcnt(0)\n\ts_barrier" ::: "memory");
    if (pf) stage(buf, (t + 2) * 64);   // overwrite cur buf: dead (all frags in regs)
    __builtin_amdgcn_s_setprio(1);
#pragma unroll
    for (int m = 0; m < 4; m++)
#pragma unroll
      for (int n = 2; n < 4; n++)
#pragma unroll
        for (int kh = 0; kh < 2; kh++)
          acc[m][n] = __builtin_amdgcn_mfma_f32_16x16x32_bf16(aF[m][kh], bF[n][kh],
                                                              acc[m][n], 0, 0, 0);
    __builtin_amdgcn_s_setprio(0);
    if (t + 1 < NT) {
      if (pf) asm volatile("s_waitcnt vmcnt(8)" ::: "memory");  // t+1's 8 loads done
      else    asm volatile("s_waitcnt vmcnt(0)" ::: "memory");
      __builtin_amdgcn_s_barrier();
      asm volatile("" ::: "memory");
    }
  }

  // epilogue: direct global stores
#pragma unroll
  for (int am = 0; am < 4; am++)
#pragma unroll
    for (int bn = 0; bn < 4; bn++) {
      int rowi = m0 + wm + am * 16 + quad * 4;
      int col = n0 + wn + bn * 16 + l15;
      float bcol = GELU ? bias[col] : 0.0f;
#pragma unroll
      for (int r = 0; r < 4; r++) {
        float val = acc[am][bn][r] + bcol;
        if (GELU) val = gelu_tanh(val);
        outz[(size_t)(rowi + r) * Nn + col] = f2bf(val);
      }
    }
}

extern "C" void kernel_launch(void* const* d_in, const int* in_sizes, int n_in,
                              void* d_out, int out_size, void* d_ws, size_t ws_size,
                              hipStream_t stream) {
  const float* q = (const float*)d_in[0];
  const float* k = (const float*)d_in[1];
  const float* v = (const float*)d_in[2];
  const float* fc1_w = (const float*)d_in[3];
  const float* fc1_b = (const float*)d_in[4];
  const float* fc2_w = (const float*)d_in[5];
  const float* fc2_b = (const float*)d_in[6];
  const float* ln1_w = (const float*)d_in[7];
  const float* ln1_b = (const float*)d_in[8];
  const float* ln2_w = (const float*)d_in[9];
  const float* ln2_b = (const float*)d_in[10];
  float* out = (float*)d_out;

  char* ws = (char*)d_ws;
  size_t off = 0;
  u16* kb = (u16*)(ws + off); off += (size_t)TT * CC * 2;         // 8 MB
  u16* vtb = (u16*)(ws + off); off += (size_t)TT * CC * 2;        // 8 MB
  u16* w1b = (u16*)(ws + off); off += (size_t)HIDE_ * CC * 2;     // 2 MB
  u16* w2b = (u16*)(ws + off); off += (size_t)CC * HIDE_ * 2;     // 2 MB
  u16* ou = (u16*)(ws + off); off += (size_t)2 * TT * CC * 2;     // 16 MB
  float* lsum = (float*)(ws + off); off += (size_t)2 * TT * HH * 4;  // 512 KB
  u16* q2b = (u16*)(ws + off); off += (size_t)TT * CC * 2;        // 8 MB
  u16* hbuf = (u16*)(ws + off); off += (size_t)TT * HIDE_ * 2;    // 32 MB
  u16* mp = (u16*)(ws + off); off += (size_t)2 * TT * CC * 2;     // 16 MB (split-K 2)

  const float QS = 0.18033688011112042f;   // (1/8) * log2(e)
  prep_kernel<<<3072, 256, 0, stream>>>(k, v, kb, vtb);
  attn_kernel<<<2048, 256, 0, stream>>>(q, kb, vtb, fc1_w, fc2_w, w1b, w2b,
                                        ou, lsum, QS);
  ln1_kernel<<<2048, 256, 0, stream>>>(q, ou, lsum, ln1_w, ln1_b, q2b);
  // fc1: M=8192, N=2048, K=512 -> 1024 blocks (gx=16, gy=64), NT=8
  gemm128<true><<<1024, 256, 0, stream>>>(q2b, w1b, fc1_b, hbuf, HIDE_, CC, 8, 16, 64);
  // fc2: M=8192, N=512, K=2048 split-K 2 -> 512 blocks (gx=4, gy=64, z=2), NT=16
  gemm128<false><<<512, 256, 0, stream>>>(hbuf, w2b, fc2_b, mp, CC, HIDE_, 16, 4, 64);
  ln2_kernel<<<2048, 256, 0, stream>>>(q2b, mp, fc2_b, ln2_w, ln2_b, out);
}

// Round 11
// 222.390 us; speedup vs baseline: 1.0244x; 1.0044x over previous
//
#include <hip/hip_runtime.h>
#include <math.h>

typedef unsigned short u16;
typedef __bf16 bf16_t;
typedef bf16_t bf16x4 __attribute__((ext_vector_type(4)));
typedef bf16_t bf16x8 __attribute__((ext_vector_type(8)));
typedef short s16x4 __attribute__((ext_vector_type(4)));
typedef float f32x4 __attribute__((ext_vector_type(4)));

typedef const __attribute__((address_space(1))) void* gcp;
typedef __attribute__((address_space(3))) void* lcp;

#define BB 4
#define NN 2048
#define CC 512
#define HH 8
#define HD 64
#define HIDE_ 2048
#define TT (BB*NN)  // 8192

#if __has_builtin(__builtin_amdgcn_exp2f)
#define EXP2(x) __builtin_amdgcn_exp2f(x)
#else
#define EXP2(x) __expf((x) * 0.69314718055994531f)
#endif

#if __has_builtin(__builtin_amdgcn_rcpf)
#define RCP(x) __builtin_amdgcn_rcpf(x)
#else
#define RCP(x) (1.0f / (x))
#endif

__device__ __forceinline__ u16 f2bf(float f) {
  unsigned u = __float_as_uint(f);
  u += 0x7FFF + ((u >> 16) & 1);   // RNE
  return (u16)(u >> 16);
}

// bijective XCD-aware block swizzle (requires nwg % 8 == 0)
__device__ __forceinline__ int xcd_swz(int orig, int nwg) {
  return (orig & 7) * (nwg >> 3) + (orig >> 3);
}

__device__ __forceinline__ void bf8_to_f(const u16* p, float* f) {
  uint4 u = *(const uint4*)p;
  f[0] = __uint_as_float(u.x << 16); f[1] = __uint_as_float(u.x & 0xffff0000u);
  f[2] = __uint_as_float(u.y << 16); f[3] = __uint_as_float(u.y & 0xffff0000u);
  f[4] = __uint_as_float(u.z << 16); f[5] = __uint_as_float(u.z & 0xffff0000u);
  f[6] = __uint_as_float(u.w << 16); f[7] = __uint_as_float(u.w & 0xffff0000u);
}

// load 8 fp32, scale, pack to bf16x8
__device__ __forceinline__ bf16x8 ldq8(const float* p, float s) {
  float4 a = *(const float4*)p;
  float4 b = *(const float4*)(p + 4);
  bf16x8 r = {(bf16_t)(a.x * s), (bf16_t)(a.y * s), (bf16_t)(a.z * s), (bf16_t)(a.w * s),
              (bf16_t)(b.x * s), (bf16_t)(b.y * s), (bf16_t)(b.z * s), (bf16_t)(b.w * s)};
  return r;
}

// tanh-form GELU
__device__ __forceinline__ float gelu_tanh(float x) {
  float y = 0.7978845608028654f * x * (1.0f + 0.044715f * x * x);
  float a = y * 2.8853900817779268f;
  a = fminf(fmaxf(a, -30.0f), 30.0f);
  float e = EXP2(a);
  float t = (e - 1.0f) * RCP(e + 1.0f);
  return 0.5f * x * (1.0f + t);
}

// ---------------- prep: k/fc1_w/fc2_w cvt + V^T transpose (vectorized) ----------------
__global__ __launch_bounds__(256) void prep_kernel(const float* __restrict__ k,
                                                   const float* __restrict__ fc1w,
                                                   const float* __restrict__ fc2w,
                                                   const float* __restrict__ v,
                                                   u16* __restrict__ kb,
                                                   u16* __restrict__ w1b,
                                                   u16* __restrict__ w2b,
                                                   u16* __restrict__ vtb) {
  __shared__ __align__(16) u16 T[64 * 72];
  int bid = blockIdx.x, tid = threadIdx.x;
  if (bid < 3072) {
    const float* in;
    u16* out;
    int rel;
    if (bid < 2048)      { in = k;    out = kb;  rel = bid; }
    else if (bid < 2560) { in = fc1w; out = w1b; rel = bid - 2048; }
    else                 { in = fc2w; out = w2b; rel = bid - 2560; }
    int i = (rel * 256 + tid) * 8;
    float4 a = *(const float4*)(in + i);
    float4 b2 = *(const float4*)(in + i + 4);
    u16 r[8] = {f2bf(a.x), f2bf(a.y), f2bf(a.z), f2bf(a.w),
                f2bf(b2.x), f2bf(b2.y), f2bf(b2.z), f2bf(b2.w)};
    *(uint4*)(out + i) = *(const uint4*)r;
    return;
  }
  int tv = bid - 3072;
  int j0 = (tv & 31) * 64;
  int bh = tv >> 5;
  int b = bh >> 3, h = bh & 7;
  // fill: float4 reads along d, transposed scalar LDS writes
#pragma unroll
  for (int i = 0; i < 4; i++) {
    int idx = i * 256 + tid;
    int j = idx >> 4, dq = idx & 15;
    float4 a = *(const float4*)(v + ((size_t)(b * NN + j0 + j)) * CC + h * 64 + dq * 4);
    T[(dq * 4 + 0) * 72 + j] = f2bf(a.x);
    T[(dq * 4 + 1) * 72 + j] = f2bf(a.y);
    T[(dq * 4 + 2) * 72 + j] = f2bf(a.z);
    T[(dq * 4 + 3) * 72 + j] = f2bf(a.w);
  }
  __syncthreads();
  // drain: uint4 (8 u16) per thread, 128B-contiguous global segments
#pragma unroll
  for (int i = 0; i < 2; i++) {
    int idx = i * 256 + tid;
    int d = idx >> 3, jb = idx & 7;
    uint4 val = *(const uint4*)&T[d * 72 + jb * 8];
    *(uint4*)&vtb[((size_t)(bh * 64 + d)) * NN + j0 + jb * 8] = val;
  }
}

// ---------------- flash attention: dual-Q-group (32 q/wave), split-K halves ----------------
// round-5 structure (best measured): KVBLK=64, single-buffer, setprio, XCD swizzle.
__global__ __launch_bounds__(256, 4) void attn_kernel(const float* __restrict__ qf,
                                                      const u16* __restrict__ kb,
                                                      const u16* __restrict__ vtb,
                                                      u16* __restrict__ ou,
                                                      float* __restrict__ lsum,
                                                      float qs) {
  __shared__ __align__(16) u16 Ks[64 * 64];
  __shared__ __align__(16) u16 Vs[64 * 64];
  int tid = threadIdx.x, wave = tid >> 6, lane = tid & 63;
  int l15 = lane & 15, quad = lane >> 4;
  int r7 = l15 & 7;
  int bid = xcd_swz(blockIdx.x, 512);
  int half = blockIdx.y;
  int qt = bid & 15, h = (bid >> 4) & 7, b = bid >> 7;
  int qw = qt * 128 + wave * 32;
  int j0base = half * 1024;

  u16* ou_ = ou + (size_t)half * TT * CC;
  float* ls_ = lsum + (size_t)half * TT * HH;

  const float* qp = qf + ((size_t)(b * NN + qw + l15)) * CC + h * 64 + quad * 8;
  bf16x8 qfA0 = ldq8(qp, qs);
  bf16x8 qfA1 = ldq8(qp + 32, qs);
  bf16x8 qfB0 = ldq8(qp + (size_t)16 * CC, qs);
  bf16x8 qfB1 = ldq8(qp + (size_t)16 * CC + 32, qs);

  int rl = lane >> 3;
  int cb = (lane & 7) ^ rl;
  int rK = wave * 16 + rl;
  size_t vtbase = ((size_t)(b * HH + h)) * 64 * NN;
  const u16* kp0 = kb + ((size_t)(b * NN + j0base + rK)) * CC + h * 64 + cb * 8;
  const u16* kp1 = kp0 + (size_t)8 * CC;
  const u16* vp0 = vtb + vtbase + (size_t)rK * NN + j0base + cb * 8;
  const u16* vp1 = vp0 + (size_t)8 * NN;
  lcp lK0 = (lcp)&Ks[wave * 16 * 64];
  lcp lK1 = (lcp)&Ks[wave * 16 * 64 + 8 * 64];
  lcp lV0 = (lcp)&Vs[wave * 16 * 64];
  lcp lV1 = (lcp)&Vs[wave * 16 * 64 + 8 * 64];

  float lA = 0.f, lB = 0.f;
  f32x4 oA[4] = {}, oB[4] = {};

  for (int kt = 0; kt < 16; kt++) {
    __syncthreads();
    __builtin_amdgcn_global_load_lds((gcp)kp0, lK0, 16, 0, 0);
    __builtin_amdgcn_global_load_lds((gcp)kp1, lK1, 16, 0, 0);
    __builtin_amdgcn_global_load_lds((gcp)vp0, lV0, 16, 0, 0);
    __builtin_amdgcn_global_load_lds((gcp)vp1, lV1, 16, 0, 0);
    kp0 += (size_t)64 * CC; kp1 += (size_t)64 * CC;
    vp0 += 64; vp1 += 64;
    __syncthreads();

    s16x4 pfA[4], pfB[4];
    __builtin_amdgcn_s_setprio(1);
#pragma unroll
    for (int nt = 0; nt < 4; nt++) {
      const u16* krow = &Ks[(nt * 16 + l15) * 64];
      bf16x8 k0 = *(const bf16x8*)&krow[(quad ^ r7) * 8];
      bf16x8 k1 = *(const bf16x8*)&krow[((quad + 4) ^ r7) * 8];
      f32x4 zA = {0.f, 0.f, 0.f, 0.f}, zB = {0.f, 0.f, 0.f, 0.f};
      zA = __builtin_amdgcn_mfma_f32_16x16x32_bf16(k0, qfA0, zA, 0, 0, 0);
      zA = __builtin_amdgcn_mfma_f32_16x16x32_bf16(k1, qfA1, zA, 0, 0, 0);
      zB = __builtin_amdgcn_mfma_f32_16x16x32_bf16(k0, qfB0, zB, 0, 0, 0);
      zB = __builtin_amdgcn_mfma_f32_16x16x32_bf16(k1, qfB1, zB, 0, 0, 0);
      float a0 = EXP2(zA[0]), a1 = EXP2(zA[1]), a2 = EXP2(zA[2]), a3 = EXP2(zA[3]);
      float b0 = EXP2(zB[0]), b1 = EXP2(zB[1]), b2 = EXP2(zB[2]), b3 = EXP2(zB[3]);
      lA += (a0 + a1) + (a2 + a3);
      lB += (b0 + b1) + (b2 + b3);
      bf16x4 ta = {(bf16_t)a0, (bf16_t)a1, (bf16_t)a2, (bf16_t)a3};
      bf16x4 tb = {(bf16_t)b0, (bf16_t)b1, (bf16_t)b2, (bf16_t)b3};
      pfA[nt] = __builtin_bit_cast(s16x4, ta);
      pfB[nt] = __builtin_bit_cast(s16x4, tb);
    }
#pragma unroll
    for (int dt = 0; dt < 4; dt++) {
      const u16* vrow = &Vs[(dt * 16 + l15) * 64];
#pragma unroll
      for (int nt = 0; nt < 4; nt++) {
        s16x4 vf = *(const s16x4*)
            &vrow[((nt * 2 + (quad >> 1)) ^ r7) * 8 + (quad & 1) * 4];
        oA[dt] = __builtin_amdgcn_mfma_f32_16x16x16bf16_1k(vf, pfA[nt], oA[dt], 0, 0, 0);
        oB[dt] = __builtin_amdgcn_mfma_f32_16x16x16bf16_1k(vf, pfB[nt], oB[dt], 0, 0, 0);
      }
    }
    __builtin_amdgcn_s_setprio(0);
  }

  lA += __shfl_xor(lA, 16, 64);
  lA += __shfl_xor(lA, 32, 64);
  lB += __shfl_xor(lB, 16, 64);
  lB += __shfl_xor(lB, 32, 64);
  if (quad == 0) {
    ls_[(size_t)(b * NN + qw + l15) * HH + h] = lA;
    ls_[(size_t)(b * NN + qw + 16 + l15) * HH + h] = lB;
  }
  size_t obase = ((size_t)(b * NN + qw + l15)) * CC + h * 64 + quad * 4;
#pragma unroll
  for (int dt = 0; dt < 4; dt++) {
    u16 ra[4] = {f2bf(oA[dt][0]), f2bf(oA[dt][1]), f2bf(oA[dt][2]), f2bf(oA[dt][3])};
    u16 rb[4] = {f2bf(oB[dt][0]), f2bf(oB[dt][1]), f2bf(oB[dt][2]), f2bf(oB[dt][3])};
    *(uint2*)&ou_[obase + dt * 16] = *(const uint2*)ra;
    *(uint2*)&ou_[obase + (size_t)16 * CC + dt * 16] = *(const uint2*)rb;
  }
}

// ---------------- ln1: combine bf16 O_u halves + fp32 q residual + LN -> bf16 ----------------
__global__ __launch_bounds__(256) void ln1_kernel(const float* __restrict__ q,
                                                  const u16* __restrict__ ou,
                                                  const float* __restrict__ lsum,
                                                  const float* __restrict__ w,
                                                  const float* __restrict__ bb,
                                                  u16* __restrict__ outb) {
  int tid = threadIdx.x;
  int row = blockIdx.x * 4 + (tid >> 6);
  int lane = tid & 63;
  int h = lane >> 3;
  size_t base = (size_t)row * CC + lane * 8;
  const u16* ou1 = ou + (size_t)TT * CC;
  const float* ls1 = lsum + (size_t)TT * HH;
  float li = lsum[(size_t)row * HH + h] + ls1[(size_t)row * HH + h];
  float inv = 1.0f / li;
  float4 a0 = *(const float4*)(q + base);
  float4 a1 = *(const float4*)(q + base + 4);
  float c[8], d[8];
  bf8_to_f(ou + base, c);
  bf8_to_f(ou1 + base, d);
  float av[8] = {a0.x, a0.y, a0.z, a0.w, a1.x, a1.y, a1.z, a1.w};
  float x[8];
#pragma unroll
  for (int i = 0; i < 8; i++) x[i] = av[i] + (c[i] + d[i]) * inv;
  float sum = 0.f, sq = 0.f;
#pragma unroll
  for (int i = 0; i < 8; i++) { sum += x[i]; sq += x[i] * x[i]; }
#pragma unroll
  for (int msk = 1; msk < 64; msk <<= 1) {
    sum += __shfl_xor(sum, msk, 64);
    sq += __shfl_xor(sq, msk, 64);
  }
  float mu = sum * (1.0f / CC);
  float var = sq * (1.0f / CC) - mu * mu;
  float rs = rsqrtf(var + 1e-6f);
  int col = lane * 8;
  float4 w0 = *(const float4*)(w + col);
  float4 w1 = *(const float4*)(w + col + 4);
  float4 b0 = *(const float4*)(bb + col);
  float4 b1 = *(const float4*)(bb + col + 4);
  float wv[8] = {w0.x, w0.y, w0.z, w0.w, w1.x, w1.y, w1.z, w1.w};
  float bv[8] = {b0.x, b0.y, b0.z, b0.w, b1.x, b1.y, b1.z, b1.w};
  u16 r[8];
#pragma unroll
  for (int i = 0; i < 8; i++) r[i] = f2bf((x[i] - mu) * rs * wv[i] + bv[i]);
  *(uint4*)(outb + base) = *(const uint4*)r;
}

// ---------------- ln2: bf16 residual + bf16 split-K partials (x2) + bias + LN ----------------
__global__ __launch_bounds__(256) void ln2_kernel(const u16* __restrict__ q2b,
                                                  const u16* __restrict__ mp,
                                                  const float* __restrict__ fb,
                                                  const float* __restrict__ w,
                                                  const float* __restrict__ bb,
                                                  float* __restrict__ outf) {
  int tid = threadIdx.x;
  int row = blockIdx.x * 4 + (tid >> 6);
  int lane = tid & 63;
  size_t base = (size_t)row * CC + lane * 8;
  const u16* mp1 = mp + (size_t)TT * CC;
  int col = lane * 8;
  float a[8], c[8], d[8];
  bf8_to_f(q2b + base, a);
  bf8_to_f(mp + base, c);
  bf8_to_f(mp1 + base, d);
  float4 f0 = *(const float4*)(fb + col);
  float4 f1 = *(const float4*)(fb + col + 4);
  float fbv[8] = {f0.x, f0.y, f0.z, f0.w, f1.x, f1.y, f1.z, f1.w};
  float x[8];
#pragma unroll
  for (int i = 0; i < 8; i++) x[i] = a[i] + (c[i] + d[i]) + fbv[i];
  float sum = 0.f, sq = 0.f;
#pragma unroll
  for (int i = 0; i < 8; i++) { sum += x[i]; sq += x[i] * x[i]; }
#pragma unroll
  for (int msk = 1; msk < 64; msk <<= 1) {
    sum += __shfl_xor(sum, msk, 64);
    sq += __shfl_xor(sq, msk, 64);
  }
  float mu = sum * (1.0f / CC);
  float var = sq * (1.0f / CC) - mu * mu;
  float rs = rsqrtf(var + 1e-6f);
  float4 w0 = *(const float4*)(w + col);
  float4 w1 = *(const float4*)(w + col + 4);
  float4 b0 = *(const float4*)(bb + col);
  float4 b1 = *(const float4*)(bb + col + 4);
  float wv[8] = {w0.x, w0.y, w0.z, w0.w, w1.x, w1.y, w1.z, w1.w};
  float bv[8] = {b0.x, b0.y, b0.z, b0.w, b1.x, b1.y, b1.z, b1.w};
  float y[8];
#pragma unroll
  for (int i = 0; i < 8; i++) y[i] = (x[i] - mu) * rs * wv[i] + bv[i];
  *(float4*)(outf + base) = make_float4(y[0], y[1], y[2], y[3]);
  *(float4*)(outf + base + 4) = make_float4(y[4], y[5], y[6], y[7]);
}

// ---------------- GEMM 128x128 tile, BK=64, 4 waves, dbuf + counted-vmcnt, 2 blocks/CU ----------
template <bool GELU>
__global__ __launch_bounds__(256) void gemm128(const u16* __restrict__ A,
                                               const u16* __restrict__ Bw,
                                               const float* __restrict__ bias,
                                               u16* __restrict__ outb,
                                               int Nn, int K, int NT,
                                               int gx, int gy) {
  __shared__ __align__(16) u16 As[2][128 * 64];
  __shared__ __align__(16) u16 Bs[2][128 * 64];
  int tid = threadIdx.x, wave = tid >> 6, lane = tid & 63;
  int l15 = lane & 15, quad = lane >> 4;
  int r7 = l15 & 7;
  int l = xcd_swz(blockIdx.x, gridDim.x);
  int bx = l % gx;
  int by = (l / gx) % gy;
  int bz = l / (gx * gy);
  int m0 = by * 128, n0 = bx * 128;
  int kbeg = bz * (NT * 64);
  u16* outz = outb + (size_t)bz * ((size_t)TT * CC);
  int wm = (wave >> 1) * 64, wn = (wave & 1) * 64;
  int w32 = wave * 32;
  int rl = lane >> 3;
  int cb = (lane & 7) ^ rl;
  const u16* Ap = &A[(size_t)(m0 + w32 + rl) * K + kbeg + cb * 8];
  const u16* Bp = &Bw[(size_t)(n0 + w32 + rl) * K + kbeg + cb * 8];
  unsigned sb = w32 * 64;   // wave's staging slice (u16 elems)

  f32x4 acc[4][4] = {};

  auto stage = [&](int buf, int kofs) {
#pragma unroll
    for (int c = 0; c < 4; c++) {
      __builtin_amdgcn_global_load_lds((gcp)(Ap + kofs + (size_t)(c * 8) * K),
          (lcp)&As[buf][sb + c * 512], 16, 0, 0);
      __builtin_amdgcn_global_load_lds((gcp)(Bp + kofs + (size_t)(c * 8) * K),
          (lcp)&Bs[buf][sb + c * 512], 16, 0, 0);
    }
  };

  // prologue: 2-deep prefetch
  stage(0, 0);
  stage(1, 64);
  asm volatile("s_waitcnt vmcnt(8)" ::: "memory");   // tile 0 complete
  __builtin_amdgcn_s_barrier();

  for (int t = 0; t < NT; t++) {
    int buf = t & 1;
    bool pf = (t + 2) < NT;
    bf16x8 aF[4][2], bF[4][2];
#pragma unroll
    for (int m = 0; m < 4; m++)
#pragma unroll
      for (int kh = 0; kh < 2; kh++)
        aF[m][kh] = *(const bf16x8*)&As[buf][(wm + m * 16 + l15) * 64 +
                                            ((kh * 4 + quad) ^ r7) * 8];
#pragma unroll
    for (int n = 0; n < 4; n++)
#pragma unroll
      for (int kh = 0; kh < 2; kh++)
        bF[n][kh] = *(const bf16x8*)&Bs[buf][(wn + n * 16 + l15) * 64 +
                                            ((kh * 4 + quad) ^ r7) * 8];
    __builtin_amdgcn_s_setprio(1);
#pragma unroll
    for (int m = 0; m < 4; m++)
#pragma unroll
      for (int n = 0; n < 2; n++)
#pragma unroll
        for (int kh = 0; kh < 2; kh++)
          acc[m][n] = __builtin_amdgcn_mfma_f32_16x16x32_bf16(aF[m][kh], bF[n][kh],
                                                              acc[m][n], 0, 0, 0);
    __builtin_amdgcn_s_setprio(0);
    // all LDS reads of buf complete (lgkmcnt 0) in every wave before anyone overwrites
    asm volatile("s_waitcnt lgkmcnt(0)\n\ts_barrier" ::: "memory");
    if (pf) stage(buf, (t + 2) * 64);   // overwrite cur buf: dead (all frags in regs)
    __builtin_amdgcn_s_setprio(1);
#pragma unroll
    for (int m = 0; m < 4; m++)
#pragma unroll
      for (int n = 2; n < 4; n++)
#pragma unroll
        for (int kh = 0; kh < 2; kh++)
          acc[m][n] = __builtin_amdgcn_mfma_f32_16x16x32_bf16(aF[m][kh], bF[n][kh],
                                                              acc[m][n], 0, 0, 0);
    __builtin_amdgcn_s_setprio(0);
    if (t + 1 < NT) {
      if (pf) asm volatile("s_waitcnt vmcnt(8)" ::: "memory");  // t+1's 8 loads done
      else    asm volatile("s_waitcnt vmcnt(0)" ::: "memory");
      __builtin_amdgcn_s_barrier();
      asm volatile("" ::: "memory");
    }
  }

  // epilogue: direct global stores
#pragma unroll
  for (int am = 0; am < 4; am++)
#pragma unroll
    for (int bn = 0; bn < 4; bn++) {
      int rowi = m0 + wm + am * 16 + quad * 4;
      int col = n0 + wn + bn * 16 + l15;
      float bcol = GELU ? bias[col] : 0.0f;
#pragma unroll
      for (int r = 0; r < 4; r++) {
        float val = acc[am][bn][r] + bcol;
        if (GELU) val = gelu_tanh(val);
        outz[(size_t)(rowi + r) * Nn + col] = f2bf(val);
      }
    }
}

extern "C" void kernel_launch(void* const* d_in, const int* in_sizes, int n_in,
                              void* d_out, int out_size, void* d_ws, size_t ws_size,
                              hipStream_t stream) {
  const float* q = (const float*)d_in[0];
  const float* k = (const float*)d_in[1];
  const float* v = (const float*)d_in[2];
  const float* fc1_w = (const float*)d_in[3];
  const float* fc1_b = (const float*)d_in[4];
  const float* fc2_w = (const float*)d_in[5];
  const float* fc2_b = (const float*)d_in[6];
  const float* ln1_w = (const float*)d_in[7];
  const float* ln1_b = (const float*)d_in[8];
  const float* ln2_w = (const float*)d_in[9];
  const float* ln2_b = (const float*)d_in[10];
  float* out = (float*)d_out;

  char* ws = (char*)d_ws;
  size_t off = 0;
  u16* kb = (u16*)(ws + off); off += (size_t)TT * CC * 2;         // 8 MB
  u16* vtb = (u16*)(ws + off); off += (size_t)TT * CC * 2;        // 8 MB
  u16* w1b = (u16*)(ws + off); off += (size_t)HIDE_ * CC * 2;     // 2 MB
  u16* w2b = (u16*)(ws + off); off += (size_t)CC * HIDE_ * 2;     // 2 MB
  u16* ou = (u16*)(ws + off); off += (size_t)2 * TT * CC * 2;     // 16 MB
  float* lsum = (float*)(ws + off); off += (size_t)2 * TT * HH * 4;  // 512 KB
  u16* q2b = (u16*)(ws + off); off += (size_t)TT * CC * 2;        // 8 MB
  u16* hbuf = (u16*)(ws + off); off += (size_t)TT * HIDE_ * 2;    // 32 MB
  u16* mp = (u16*)(ws + off); off += (size_t)2 * TT * CC * 2;     // 16 MB (split-K 2)

  const float QS = 0.18033688011112042f;   // (1/8) * log2(e)
  prep_kernel<<<4096, 256, 0, stream>>>(k, fc1_w, fc2_w, v, kb, w1b, w2b, vtb);
  attn_kernel<<<dim3(512, 2), 256, 0, stream>>>(q, kb, vtb, ou, lsum, QS);
  ln1_kernel<<<2048, 256, 0, stream>>>(q, ou, lsum, ln1_w, ln1_b, q2b);
  // fc1: M=8192, N=2048, K=512 -> 1024 blocks (gx=16, gy=64), NT=8
  gemm128<true><<<1024, 256, 0, stream>>>(q2b, w1b, fc1_b, hbuf, HIDE_, CC, 8, 16, 64);
  // fc2: M=8192, N=512, K=2048 split-K 2 -> 512 blocks (gx=4, gy=64, z=2), NT=16
  gemm128<false><<<512, 256, 0, stream>>>(hbuf, w2b, fc2_b, mp, CC, HIDE_, 16, 4, 64);
  ln2_kernel<<<2048, 256, 0, stream>>>(q2b, mp, fc2_b, ln2_w, ln2_b, out);
}

// Round 12
// 218.970 us; speedup vs baseline: 1.0404x; 1.0156x over previous
//
#include <hip/hip_runtime.h>
#include <math.h>

typedef unsigned short u16;
typedef __bf16 bf16_t;
typedef bf16_t bf16x4 __attribute__((ext_vector_type(4)));
typedef bf16_t bf16x8 __attribute__((ext_vector_type(8)));
typedef short s16x4 __attribute__((ext_vector_type(4)));
typedef float f32x4 __attribute__((ext_vector_type(4)));

typedef const __attribute__((address_space(1))) void* gcp;
typedef __attribute__((address_space(3))) void* lcp;

#define BB 4
#define NN 2048
#define CC 512
#define HH 8
#define HD 64
#define HIDE_ 2048
#define TT (BB*NN)  // 8192

#if __has_builtin(__builtin_amdgcn_exp2f)
#define EXP2(x) __builtin_amdgcn_exp2f(x)
#else
#define EXP2(x) __expf((x) * 0.69314718055994531f)
#endif

#if __has_builtin(__builtin_amdgcn_rcpf)
#define RCP(x) __builtin_amdgcn_rcpf(x)
#else
#define RCP(x) (1.0f / (x))
#endif

__device__ __forceinline__ u16 f2bf(float f) {
  unsigned u = __float_as_uint(f);
  u += 0x7FFF + ((u >> 16) & 1);   // RNE
  return (u16)(u >> 16);
}

// bijective XCD-aware block swizzle (requires nwg % 8 == 0)
__device__ __forceinline__ int xcd_swz(int orig, int nwg) {
  return (orig & 7) * (nwg >> 3) + (orig >> 3);
}

__device__ __forceinline__ void bf8_to_f(const u16* p, float* f) {
  uint4 u = *(const uint4*)p;
  f[0] = __uint_as_float(u.x << 16); f[1] = __uint_as_float(u.x & 0xffff0000u);
  f[2] = __uint_as_float(u.y << 16); f[3] = __uint_as_float(u.y & 0xffff0000u);
  f[4] = __uint_as_float(u.z << 16); f[5] = __uint_as_float(u.z & 0xffff0000u);
  f[6] = __uint_as_float(u.w << 16); f[7] = __uint_as_float(u.w & 0xffff0000u);
}

// load 8 fp32, scale, pack to bf16x8
__device__ __forceinline__ bf16x8 ldq8(const float* p, float s) {
  float4 a = *(const float4*)p;
  float4 b = *(const float4*)(p + 4);
  bf16x8 r = {(bf16_t)(a.x * s), (bf16_t)(a.y * s), (bf16_t)(a.z * s), (bf16_t)(a.w * s),
              (bf16_t)(b.x * s), (bf16_t)(b.y * s), (bf16_t)(b.z * s), (bf16_t)(b.w * s)};
  return r;
}

// tanh-form GELU
__device__ __forceinline__ float gelu_tanh(float x) {
  float y = 0.7978845608028654f * x * (1.0f + 0.044715f * x * x);
  float a = y * 2.8853900817779268f;
  a = fminf(fmaxf(a, -30.0f), 30.0f);
  float e = EXP2(a);
  float t = (e - 1.0f) * RCP(e + 1.0f);
  return 0.5f * x * (1.0f + t);
}

// ---------------- prep: k/fc1_w/fc2_w cvt + V^T transpose (vectorized) ----------------
__global__ __launch_bounds__(256) void prep_kernel(const float* __restrict__ k,
                                                   const float* __restrict__ fc1w,
                                                   const float* __restrict__ fc2w,
                                                   const float* __restrict__ v,
                                                   u16* __restrict__ kb,
                                                   u16* __restrict__ w1b,
                                                   u16* __restrict__ w2b,
                                                   u16* __restrict__ vtb) {
  __shared__ __align__(16) u16 T[64 * 72];
  int bid = blockIdx.x, tid = threadIdx.x;
  if (bid < 3072) {
    const float* in;
    u16* out;
    int rel;
    if (bid < 2048)      { in = k;    out = kb;  rel = bid; }
    else if (bid < 2560) { in = fc1w; out = w1b; rel = bid - 2048; }
    else                 { in = fc2w; out = w2b; rel = bid - 2560; }
    int i = (rel * 256 + tid) * 8;
    float4 a = *(const float4*)(in + i);
    float4 b2 = *(const float4*)(in + i + 4);
    u16 r[8] = {f2bf(a.x), f2bf(a.y), f2bf(a.z), f2bf(a.w),
                f2bf(b2.x), f2bf(b2.y), f2bf(b2.z), f2bf(b2.w)};
    *(uint4*)(out + i) = *(const uint4*)r;
    return;
  }
  int tv = bid - 3072;
  int j0 = (tv & 31) * 64;
  int bh = tv >> 5;
  int b = bh >> 3, h = bh & 7;
  // fill: float4 reads along d, transposed scalar LDS writes
#pragma unroll
  for (int i = 0; i < 4; i++) {
    int idx = i * 256 + tid;
    int j = idx >> 4, dq = idx & 15;
    float4 a = *(const float4*)(v + ((size_t)(b * NN + j0 + j)) * CC + h * 64 + dq * 4);
    T[(dq * 4 + 0) * 72 + j] = f2bf(a.x);
    T[(dq * 4 + 1) * 72 + j] = f2bf(a.y);
    T[(dq * 4 + 2) * 72 + j] = f2bf(a.z);
    T[(dq * 4 + 3) * 72 + j] = f2bf(a.w);
  }
  __syncthreads();
  // drain: uint4 (8 u16) per thread, 128B-contiguous global segments
#pragma unroll
  for (int i = 0; i < 2; i++) {
    int idx = i * 256 + tid;
    int d = idx >> 3, jb = idx & 7;
    uint4 val = *(const uint4*)&T[d * 72 + jb * 8];
    *(uint4*)&vtb[((size_t)(bh * 64 + d)) * NN + j0 + jb * 8] = val;
  }
}

// ---------------- flash attention: dual-Q-group (32 q/wave), full-K (split-K 1) ----------------
// Per-block full softmax row -> normalize in-register in the epilogue, write ONE bf16
// O slab (16 MB not 32), no lsum. Same per-tile loop body as the proven round-5 kernel.
__global__ __launch_bounds__(256, 4) void attn_kernel(const float* __restrict__ qf,
                                                      const u16* __restrict__ kb,
                                                      const u16* __restrict__ vtb,
                                                      u16* __restrict__ ou,
                                                      float qs) {
  __shared__ __align__(16) u16 Ks[64 * 64];
  __shared__ __align__(16) u16 Vs[64 * 64];
  int tid = threadIdx.x, wave = tid >> 6, lane = tid & 63;
  int l15 = lane & 15, quad = lane >> 4;
  int r7 = l15 & 7;
  int bid = xcd_swz(blockIdx.x, 512);
  int qt = bid & 15, h = (bid >> 4) & 7, b = bid >> 7;
  int qw = qt * 128 + wave * 32;

  const float* qp = qf + ((size_t)(b * NN + qw + l15)) * CC + h * 64 + quad * 8;
  bf16x8 qfA0 = ldq8(qp, qs);
  bf16x8 qfA1 = ldq8(qp + 32, qs);
  bf16x8 qfB0 = ldq8(qp + (size_t)16 * CC, qs);
  bf16x8 qfB1 = ldq8(qp + (size_t)16 * CC + 32, qs);

  int rl = lane >> 3;
  int cb = (lane & 7) ^ rl;
  int rK = wave * 16 + rl;
  size_t vtbase = ((size_t)(b * HH + h)) * 64 * NN;
  const u16* kp0 = kb + ((size_t)(b * NN + rK)) * CC + h * 64 + cb * 8;
  const u16* kp1 = kp0 + (size_t)8 * CC;
  const u16* vp0 = vtb + vtbase + (size_t)rK * NN + cb * 8;
  const u16* vp1 = vp0 + (size_t)8 * NN;
  lcp lK0 = (lcp)&Ks[wave * 16 * 64];
  lcp lK1 = (lcp)&Ks[wave * 16 * 64 + 8 * 64];
  lcp lV0 = (lcp)&Vs[wave * 16 * 64];
  lcp lV1 = (lcp)&Vs[wave * 16 * 64 + 8 * 64];

  float lA = 0.f, lB = 0.f;
  f32x4 oA[4] = {}, oB[4] = {};

  for (int kt = 0; kt < 32; kt++) {
    __syncthreads();
    __builtin_amdgcn_global_load_lds((gcp)kp0, lK0, 16, 0, 0);
    __builtin_amdgcn_global_load_lds((gcp)kp1, lK1, 16, 0, 0);
    __builtin_amdgcn_global_load_lds((gcp)vp0, lV0, 16, 0, 0);
    __builtin_amdgcn_global_load_lds((gcp)vp1, lV1, 16, 0, 0);
    kp0 += (size_t)64 * CC; kp1 += (size_t)64 * CC;
    vp0 += 64; vp1 += 64;
    __syncthreads();

    s16x4 pfA[4], pfB[4];
    __builtin_amdgcn_s_setprio(1);
#pragma unroll
    for (int nt = 0; nt < 4; nt++) {
      const u16* krow = &Ks[(nt * 16 + l15) * 64];
      bf16x8 k0 = *(const bf16x8*)&krow[(quad ^ r7) * 8];
      bf16x8 k1 = *(const bf16x8*)&krow[((quad + 4) ^ r7) * 8];
      f32x4 zA = {0.f, 0.f, 0.f, 0.f}, zB = {0.f, 0.f, 0.f, 0.f};
      zA = __builtin_amdgcn_mfma_f32_16x16x32_bf16(k0, qfA0, zA, 0, 0, 0);
      zA = __builtin_amdgcn_mfma_f32_16x16x32_bf16(k1, qfA1, zA, 0, 0, 0);
      zB = __builtin_amdgcn_mfma_f32_16x16x32_bf16(k0, qfB0, zB, 0, 0, 0);
      zB = __builtin_amdgcn_mfma_f32_16x16x32_bf16(k1, qfB1, zB, 0, 0, 0);
      float a0 = EXP2(zA[0]), a1 = EXP2(zA[1]), a2 = EXP2(zA[2]), a3 = EXP2(zA[3]);
      float b0 = EXP2(zB[0]), b1 = EXP2(zB[1]), b2 = EXP2(zB[2]), b3 = EXP2(zB[3]);
      lA += (a0 + a1) + (a2 + a3);
      lB += (b0 + b1) + (b2 + b3);
      bf16x4 ta = {(bf16_t)a0, (bf16_t)a1, (bf16_t)a2, (bf16_t)a3};
      bf16x4 tb = {(bf16_t)b0, (bf16_t)b1, (bf16_t)b2, (bf16_t)b3};
      pfA[nt] = __builtin_bit_cast(s16x4, ta);
      pfB[nt] = __builtin_bit_cast(s16x4, tb);
    }
#pragma unroll
    for (int dt = 0; dt < 4; dt++) {
      const u16* vrow = &Vs[(dt * 16 + l15) * 64];
#pragma unroll
      for (int nt = 0; nt < 4; nt++) {
        s16x4 vf = *(const s16x4*)
            &vrow[((nt * 2 + (quad >> 1)) ^ r7) * 8 + (quad & 1) * 4];
        oA[dt] = __builtin_amdgcn_mfma_f32_16x16x16bf16_1k(vf, pfA[nt], oA[dt], 0, 0, 0);
        oB[dt] = __builtin_amdgcn_mfma_f32_16x16x16bf16_1k(vf, pfB[nt], oB[dt], 0, 0, 0);
      }
    }
    __builtin_amdgcn_s_setprio(0);
  }

  // full row sums: after the butterfly every lane holds its q-row's denominator
  lA += __shfl_xor(lA, 16, 64);
  lA += __shfl_xor(lA, 32, 64);
  lB += __shfl_xor(lB, 16, 64);
  lB += __shfl_xor(lB, 32, 64);
  float invA = 1.0f / lA;
  float invB = 1.0f / lB;
  size_t obase = ((size_t)(b * NN + qw + l15)) * CC + h * 64 + quad * 4;
#pragma unroll
  for (int dt = 0; dt < 4; dt++) {
    u16 ra[4] = {f2bf(oA[dt][0] * invA), f2bf(oA[dt][1] * invA),
                 f2bf(oA[dt][2] * invA), f2bf(oA[dt][3] * invA)};
    u16 rb[4] = {f2bf(oB[dt][0] * invB), f2bf(oB[dt][1] * invB),
                 f2bf(oB[dt][2] * invB), f2bf(oB[dt][3] * invB)};
    *(uint2*)&ou[obase + dt * 16] = *(const uint2*)ra;
    *(uint2*)&ou[obase + (size_t)16 * CC + dt * 16] = *(const uint2*)rb;
  }
}

// ---------------- ln1: bf16 normalized O + fp32 q residual + LN -> bf16 ----------------
__global__ __launch_bounds__(256) void ln1_kernel(const float* __restrict__ q,
                                                  const u16* __restrict__ ou,
                                                  const float* __restrict__ w,
                                                  const float* __restrict__ bb,
                                                  u16* __restrict__ outb) {
  int tid = threadIdx.x;
  int row = blockIdx.x * 4 + (tid >> 6);
  int lane = tid & 63;
  size_t base = (size_t)row * CC + lane * 8;
  float4 a0 = *(const float4*)(q + base);
  float4 a1 = *(const float4*)(q + base + 4);
  float c[8];
  bf8_to_f(ou + base, c);
  float av[8] = {a0.x, a0.y, a0.z, a0.w, a1.x, a1.y, a1.z, a1.w};
  float x[8];
#pragma unroll
  for (int i = 0; i < 8; i++) x[i] = av[i] + c[i];
  float sum = 0.f, sq = 0.f;
#pragma unroll
  for (int i = 0; i < 8; i++) { sum += x[i]; sq += x[i] * x[i]; }
#pragma unroll
  for (int msk = 1; msk < 64; msk <<= 1) {
    sum += __shfl_xor(sum, msk, 64);
    sq += __shfl_xor(sq, msk, 64);
  }
  float mu = sum * (1.0f / CC);
  float var = sq * (1.0f / CC) - mu * mu;
  float rs = rsqrtf(var + 1e-6f);
  int col = lane * 8;
  float4 w0 = *(const float4*)(w + col);
  float4 w1 = *(const float4*)(w + col + 4);
  float4 b0 = *(const float4*)(bb + col);
  float4 b1 = *(const float4*)(bb + col + 4);
  float wv[8] = {w0.x, w0.y, w0.z, w0.w, w1.x, w1.y, w1.z, w1.w};
  float bv[8] = {b0.x, b0.y, b0.z, b0.w, b1.x, b1.y, b1.z, b1.w};
  u16 r[8];
#pragma unroll
  for (int i = 0; i < 8; i++) r[i] = f2bf((x[i] - mu) * rs * wv[i] + bv[i]);
  *(uint4*)(outb + base) = *(const uint4*)r;
}

// ---------------- ln2: bf16 residual + bf16 split-K partials (x2) + bias + LN ----------------
__global__ __launch_bounds__(256) void ln2_kernel(const u16* __restrict__ q2b,
                                                  const u16* __restrict__ mp,
                                                  const float* __restrict__ fb,
                                                  const float* __restrict__ w,
                                                  const float* __restrict__ bb,
                                                  float* __restrict__ outf) {
  int tid = threadIdx.x;
  int row = blockIdx.x * 4 + (tid >> 6);
  int lane = tid & 63;
  size_t base = (size_t)row * CC + lane * 8;
  const u16* mp1 = mp + (size_t)TT * CC;
  int col = lane * 8;
  float a[8], c[8], d[8];
  bf8_to_f(q2b + base, a);
  bf8_to_f(mp + base, c);
  bf8_to_f(mp1 + base, d);
  float4 f0 = *(const float4*)(fb + col);
  float4 f1 = *(const float4*)(fb + col + 4);
  float fbv[8] = {f0.x, f0.y, f0.z, f0.w, f1.x, f1.y, f1.z, f1.w};
  float x[8];
#pragma unroll
  for (int i = 0; i < 8; i++) x[i] = a[i] + (c[i] + d[i]) + fbv[i];
  float sum = 0.f, sq = 0.f;
#pragma unroll
  for (int i = 0; i < 8; i++) { sum += x[i]; sq += x[i] * x[i]; }
#pragma unroll
  for (int msk = 1; msk < 64; msk <<= 1) {
    sum += __shfl_xor(sum, msk, 64);
    sq += __shfl_xor(sq, msk, 64);
  }
  float mu = sum * (1.0f / CC);
  float var = sq * (1.0f / CC) - mu * mu;
  float rs = rsqrtf(var + 1e-6f);
  float4 w0 = *(const float4*)(w + col);
  float4 w1 = *(const float4*)(w + col + 4);
  float4 b0 = *(const float4*)(bb + col);
  float4 b1 = *(const float4*)(bb + col + 4);
  float wv[8] = {w0.x, w0.y, w0.z, w0.w, w1.x, w1.y, w1.z, w1.w};
  float bv[8] = {b0.x, b0.y, b0.z, b0.w, b1.x, b1.y, b1.z, b1.w};
  float y[8];
#pragma unroll
  for (int i = 0; i < 8; i++) y[i] = (x[i] - mu) * rs * wv[i] + bv[i];
  *(float4*)(outf + base) = make_float4(y[0], y[1], y[2], y[3]);
  *(float4*)(outf + base + 4) = make_float4(y[4], y[5], y[6], y[7]);
}

// ---------------- GEMM 128x128 tile, BK=64, 4 waves, dbuf + counted-vmcnt, 2 blocks/CU ----------
template <bool GELU>
__global__ __launch_bounds__(256) void gemm128(const u16* __restrict__ A,
                                               const u16* __restrict__ Bw,
                                               const float* __restrict__ bias,
                                               u16* __restrict__ outb,
                                               int Nn, int K, int NT,
                                               int gx, int gy) {
  __shared__ __align__(16) u16 As[2][128 * 64];
  __shared__ __align__(16) u16 Bs[2][128 * 64];
  int tid = threadIdx.x, wave = tid >> 6, lane = tid & 63;
  int l15 = lane & 15, quad = lane >> 4;
  int r7 = l15 & 7;
  int l = xcd_swz(blockIdx.x, gridDim.x);
  int bx = l % gx;
  int by = (l / gx) % gy;
  int bz = l / (gx * gy);
  int m0 = by * 128, n0 = bx * 128;
  int kbeg = bz * (NT * 64);
  u16* outz = outb + (size_t)bz * ((size_t)TT * CC);
  int wm = (wave >> 1) * 64, wn = (wave & 1) * 64;
  int w32 = wave * 32;
  int rl = lane >> 3;
  int cb = (lane & 7) ^ rl;
  const u16* Ap = &A[(size_t)(m0 + w32 + rl) * K + kbeg + cb * 8];
  const u16* Bp = &Bw[(size_t)(n0 + w32 + rl) * K + kbeg + cb * 8];
  unsigned sb = w32 * 64;   // wave's staging slice (u16 elems)

  f32x4 acc[4][4] = {};

  auto stage = [&](int buf, int kofs) {
#pragma unroll
    for (int c = 0; c < 4; c++) {
      __builtin_amdgcn_global_load_lds((gcp)(Ap + kofs + (size_t)(c * 8) * K),
          (lcp)&As[buf][sb + c * 512], 16, 0, 0);
      __builtin_amdgcn_global_load_lds((gcp)(Bp + kofs + (size_t)(c * 8) * K),
          (lcp)&Bs[buf][sb + c * 512], 16, 0, 0);
    }
  };

  // prologue: 2-deep prefetch
  stage(0, 0);
  stage(1, 64);
  asm volatile("s_waitcnt vmcnt(8)" ::: "memory");   // tile 0 complete
  __builtin_amdgcn_s_barrier();

  for (int t = 0; t < NT; t++) {
    int buf = t & 1;
    bool pf = (t + 2) < NT;
    bf16x8 aF[4][2], bF[4][2];
#pragma unroll
    for (int m = 0; m < 4; m++)
#pragma unroll
      for (int kh = 0; kh < 2; kh++)
        aF[m][kh] = *(const bf16x8*)&As[buf][(wm + m * 16 + l15) * 64 +
                                            ((kh * 4 + quad) ^ r7) * 8];
#pragma unroll
    for (int n = 0; n < 4; n++)
#pragma unroll
      for (int kh = 0; kh < 2; kh++)
        bF[n][kh] = *(const bf16x8*)&Bs[buf][(wn + n * 16 + l15) * 64 +
                                            ((kh * 4 + quad) ^ r7) * 8];
    __builtin_amdgcn_s_setprio(1);
#pragma unroll
    for (int m = 0; m < 4; m++)
#pragma unroll
      for (int n = 0; n < 2; n++)
#pragma unroll
        for (int kh = 0; kh < 2; kh++)
          acc[m][n] = __builtin_amdgcn_mfma_f32_16x16x32_bf16(aF[m][kh], bF[n][kh],
                                                              acc[m][n], 0, 0, 0);
    __builtin_amdgcn_s_setprio(0);
    // all LDS reads of buf complete (lgkmcnt 0) in every wave before anyone overwrites
    asm volatile("s_waitcnt lgkmcnt(0)\n\ts_barrier" ::: "memory");
    if (pf) stage(buf, (t + 2) * 64);   // overwrite cur buf: dead (all frags in regs)
    __builtin_amdgcn_s_setprio(1);
#pragma unroll
    for (int m = 0; m < 4; m++)
#pragma unroll
      for (int n = 2; n < 4; n++)
#pragma unroll
        for (int kh = 0; kh < 2; kh++)
          acc[m][n] = __builtin_amdgcn_mfma_f32_16x16x32_bf16(aF[m][kh], bF[n][kh],
                                                              acc[m][n], 0, 0, 0);
    __builtin_amdgcn_s_setprio(0);
    if (t + 1 < NT) {
      if (pf) asm volatile("s_waitcnt vmcnt(8)" ::: "memory");  // t+1's 8 loads done
      else    asm volatile("s_waitcnt vmcnt(0)" ::: "memory");
      __builtin_amdgcn_s_barrier();
      asm volatile("" ::: "memory");
    }
  }

  // epilogue: direct global stores
#pragma unroll
  for (int am = 0; am < 4; am++)
#pragma unroll
    for (int bn = 0; bn < 4; bn++) {
      int rowi = m0 + wm + am * 16 + quad * 4;
      int col = n0 + wn + bn * 16 + l15;
      float bcol = GELU ? bias[col] : 0.0f;
#pragma unroll
      for (int r = 0; r < 4; r++) {
        float val = acc[am][bn][r] + bcol;
        if (GELU) val = gelu_tanh(val);
        outz[(size_t)(rowi + r) * Nn + col] = f2bf(val);
      }
    }
}

extern "C" void kernel_launch(void* const* d_in, const int* in_sizes, int n_in,
                              void* d_out, int out_size, void* d_ws, size_t ws_size,
                              hipStream_t stream) {
  const float* q = (const float*)d_in[0];
  const float* k = (const float*)d_in[1];
  const float* v = (const float*)d_in[2];
  const float* fc1_w = (const float*)d_in[3];
  const float* fc1_b = (const float*)d_in[4];
  const float* fc2_w = (const float*)d_in[5];
  const float* fc2_b = (const float*)d_in[6];
  const float* ln1_w = (const float*)d_in[7];
  const float* ln1_b = (const float*)d_in[8];
  const float* ln2_w = (const float*)d_in[9];
  const float* ln2_b = (const float*)d_in[10];
  float* out = (float*)d_out;

  char* ws = (char*)d_ws;
  size_t off = 0;
  u16* kb = (u16*)(ws + off); off += (size_t)TT * CC * 2;         // 8 MB
  u16* vtb = (u16*)(ws + off); off += (size_t)TT * CC * 2;        // 8 MB
  u16* w1b = (u16*)(ws + off); off += (size_t)HIDE_ * CC * 2;     // 2 MB
  u16* w2b = (u16*)(ws + off); off += (size_t)CC * HIDE_ * 2;     // 2 MB
  u16* ou = (u16*)(ws + off); off += (size_t)TT * CC * 2;         // 8 MB (normalized O)
  u16* q2b = (u16*)(ws + off); off += (size_t)TT * CC * 2;        // 8 MB
  u16* hbuf = (u16*)(ws + off); off += (size_t)TT * HIDE_ * 2;    // 32 MB
  u16* mp = (u16*)(ws + off); off += (size_t)2 * TT * CC * 2;     // 16 MB (split-K 2)

  const float QS = 0.18033688011112042f;   // (1/8) * log2(e)
  prep_kernel<<<4096, 256, 0, stream>>>(k, fc1_w, fc2_w, v, kb, w1b, w2b, vtb);
  attn_kernel<<<512, 256, 0, stream>>>(q, kb, vtb, ou, QS);
  ln1_kernel<<<2048, 256, 0, stream>>>(q, ou, ln1_w, ln1_b, q2b);
  // fc1: M=8192, N=2048, K=512 -> 1024 blocks (gx=16, gy=64), NT=8
  gemm128<true><<<1024, 256, 0, stream>>>(q2b, w1b, fc1_b, hbuf, HIDE_, CC, 8, 16, 64);
  // fc2: M=8192, N=512, K=2048 split-K 2 -> 512 blocks (gx=4, gy=64, z=2), NT=16
  gemm128<false><<<512, 256, 0, stream>>>(hbuf, w2b, fc2_b, mp, CC, HIDE_, 16, 4, 64);
  ln2_kernel<<<2048, 256, 0, stream>>>(q2b, mp, fc2_b, ln2_w, ln2_b, out);
}